// Round 1
// baseline (393.209 us; speedup 1.0000x reference)
//
#include <hip/hip_runtime.h>
#include <cmath>

// Forbid FMA contraction: the reference check is a float32 numpy replay with
// individually-rounded ops. We opt into FMA explicitly (fmaf) only where
// BLAS sgemm itself uses an FMA chain.
#pragma clang fp contract(off)

#define NLV 16
#define TSZ (1u << 19)
#define TMASK (TSZ - 1u)
#define PR1 2654435761u
#define PR2 805459861u

typedef float v2f __attribute__((ext_vector_type(2)));
typedef float v4f __attribute__((ext_vector_type(4)));

struct ResT { float r[NLV]; };

// ---------- shared helpers (bit-exact fp32, matches np reference) ----------
__device__ __forceinline__ void aabb_norm(
    const float* __restrict__ g_aabb, float posx, float posy, float posz,
    float& s0, float& s1, float& s2,
    float& pnx, float& pny, float& pnz, bool& sel)
{
    float a0 = g_aabb[0], a1 = g_aabb[1], a2 = g_aabb[2];
    s0 = fmaxf(g_aabb[3] - a0, 1e-6f);
    s1 = fmaxf(g_aabb[4] - a1, 1e-6f);
    s2 = fmaxf(g_aabb[5] - a2, 1e-6f);
    float nx = (posx - a0) / s0;
    float ny = (posy - a1) / s1;
    float nz = (posz - a2) / s2;
    sel = (nx >= 0.f) && (nx <= 1.f) && (ny >= 0.f) && (ny <= 1.f)
       && (nz >= 0.f) && (nz <= 1.f);
    pnx = fminf(fmaxf(nx, 0.f), 1.f);
    pny = fminf(fmaxf(ny, 0.f), 1.f);
    pnz = fminf(fmaxf(nz, 0.f), 1.f);
}

// =====================================================================
// PASS A: one (point, level) per thread.
// TIME-PHASED XCD MAPPING: blocks [0, 8*chunks) cover levels 0..7 with
// lvl = b&7 (XCD round-robin b%8 => level l pinned to XCD l). Blocks
// [8*chunks, 16*chunks) cover levels 8..15 the same way. At any instant
// each XCD works a SINGLE 4 MB table slice -> slice is L2-resident
// (previously levels l and l+8 shared one XCD: 8 MB in 4 MB L2 = thrash).
// Workspace written with NON-TEMPORAL stores so the 131 MB stream does
// not evict the table slice. ws layout packed for pass B:
//   f2[l*N+n]  = (f0,f1)           (v2f plane)
//   p4[l*N+n]  = (xa,xb,ya,yb)     (v4f plane)
//   p2[l*N+n]  = (za,zb)           (v2f plane)
// =====================================================================
__global__ __launch_bounds__(256) void level_gather(
    const float* __restrict__ g_pos,
    const float* __restrict__ g_tab,
    const float* __restrict__ g_aabb,
    float* __restrict__ ws,
    int N, int chunks, ResT rt)
{
    int b = blockIdx.x;
    int half = (b >= 8 * chunks) ? 1 : 0;
    int bb = b - half * (8 * chunks);
    int lvl = (bb & 7) + (half << 3);
    int n = (bb >> 3) * 256 + threadIdx.x;
    if (n >= N) return;

    float posx = g_pos[3*n+0], posy = g_pos[3*n+1], posz = g_pos[3*n+2];
    float s0, s1, s2, pnx, pny, pnz; bool sel;
    aabb_norm(g_aabb, posx, posy, posz, s0, s1, s2, pnx, pny, pnz, sel);

    float res = rt.r[lvl];                       // wave-uniform scalar
    const float2* tl = (const float2*)g_tab + (size_t)lvl * TSZ;

    float fx = pnx * res, fy = pny * res, fz = pnz * res;
    float x0 = floorf(fx), y0 = floorf(fy), z0 = floorf(fz);
    float wx = fx - x0, wy = fy - y0, wz = fz - z0;
    float omx = 1.f - wx, omy = 1.f - wy, omz = 1.f - wz;
    unsigned ux = (unsigned)x0, uy = (unsigned)y0, uz = (unsigned)z0;
    unsigned hx0 = ux,        hx1 = ux + 1u;
    unsigned hy0 = uy * PR1,  hy1 = (uy + 1u) * PR1;
    unsigned hz0 = uz * PR2,  hz1 = (uz + 1u) * PR2;
    float f0 = 0.f, f1 = 0.f;
    float lxa = 0.f, lxb = 0.f, lya = 0.f, lyb = 0.f, lza = 0.f, lzb = 0.f;
#pragma unroll
    for (int c = 0; c < 8; ++c) {
        unsigned hh = ((c & 4) ? hx1 : hx0) ^ ((c & 2) ? hy1 : hy0) ^ ((c & 1) ? hz1 : hz0);
        float2 fv = tl[hh & TMASK];
        float wxv = (c & 4) ? wx : omx;
        float wyv = (c & 2) ? wy : omy;
        float wzv = (c & 1) ? wz : omz;
        // forward: wc = (x*y)*z, each op rounded; f += fv*wc seq c=0..7
        float wgt = wxv * wyv;
        wgt = wgt * wzv;
        float t0 = fv.x * wgt;
        float t1 = fv.y * wgt;
        f0 = f0 + t0;
        f1 = f1 + t1;
        // gradient partials (sign flip by corner bit is exact)
        float pyz = wyv * wzv;
        float pxz = wxv * wzv;
        float pxy = wxv * wyv;
        float spx = (c & 4) ? pyz : -pyz;
        float spy = (c & 2) ? pxz : -pxz;
        float spz = (c & 1) ? pxy : -pxy;
        lxa = lxa + fv.x * spx;  lxb = lxb + fv.y * spx;
        lya = lya + fv.x * spy;  lyb = lyb + fv.y * spy;
        lza = lza + fv.x * spz;  lzb = lzb + fv.y * spz;
    }

    size_t LN = (size_t)NLV * N;
    size_t idx = (size_t)lvl * N + n;
    v2f* f2 = (v2f*)ws;                  // 2*LN floats
    v4f* p4 = (v4f*)(ws + 2*LN);         // 4*LN floats
    v2f* p2 = (v2f*)(ws + 6*LN);         // 2*LN floats
    v2f ff = {f0, f1};
    v4f pa = {lxa, lxb, lya, lyb};
    v2f pz = {lza, lzb};
    __builtin_nontemporal_store(ff, f2 + idx);
    __builtin_nontemporal_store(pa, p4 + idx);
    __builtin_nontemporal_store(pz, p2 + idx);
}

// =====================================================================
// PASS B: one thread per point. No table access; streams f/partials
// from workspace (non-temporal, packed wide loads, prefetched), replays
// the exact reference z1/sh chain, backward.
// =====================================================================
__global__ __launch_bounds__(256) void mlp_bwd(
    const float* __restrict__ g_pos,
    const float* __restrict__ g_rx,
    const float* __restrict__ g_W1,
    const float* __restrict__ g_W2,
    const float* __restrict__ g_aabb,
    const int*   __restrict__ g_deg,
    const float* __restrict__ ws,
    float* __restrict__ g_out,
    int N, ResT rt)
{
    int n = blockIdx.x * 256 + threadIdx.x;
    if (n >= N) return;

    float posx = g_pos[3*n+0], posy = g_pos[3*n+1], posz = g_pos[3*n+2];
    float s0, s1, s2, pnx, pny, pnz; bool sel;
    aabb_norm(g_aabb, posx, posy, posz, s0, s1, s2, pnx, pny, pnz, sel);
    (void)pnx; (void)pny; (void)pnz;

    size_t LN = (size_t)NLV * N;
    const v2f* f2 = (const v2f*)ws;
    const v4f* p4 = (const v4f*)(ws + 2*LN);
    const v2f* p2 = (const v2f*)(ws + 6*LN);

    // prefetch ALL (f0,f1) pairs: 16 independent 8B coalesced loads in flight
    v2f fv[NLV];
#pragma unroll
    for (int l = 0; l < NLV; ++l)
        fv[l] = __builtin_nontemporal_load(f2 + (size_t)l * N + n);

    // ---- z1 = feats@W1, exact level order, sgemm FMA chain ascending k ----
    float z1[32];
#pragma unroll
    for (int i = 0; i < 32; ++i) z1[i] = 0.f;
#pragma unroll
    for (int l = 0; l < NLV; ++l) {
        float f0 = fv[l].x;
        float f1 = fv[l].y;
        const float* w1a = g_W1 + (2*l) * 32;
        const float* w1b = g_W1 + (2*l+1) * 32;
#pragma unroll
        for (int i = 0; i < 32; ++i) {
            float acc = fmaf(f0, w1a[i], z1[i]);   // k=2l then k=2l+1
            z1[i] = fmaf(f1, w1b[i], acc);
        }
    }

    // ---- relu + second layer (sgemm FMA chain, ascending j) ----
    unsigned mask = 0u;
    float sh[32];
#pragma unroll
    for (int o = 0; o < 32; ++o) sh[o] = 0.f;
#pragma unroll
    for (int i = 0; i < 32; ++i) {
        bool on = (z1[i] > 0.f);
        if (on) mask |= (1u << i);
        float h = on ? z1[i] : 0.f;
        const float* w2r = g_W2 + i * 32;
#pragma unroll
        for (int o = 0; o < 32; ++o) sh[o] = fmaf(h, w2r[o], sh[o]);
    }

    const float C0c = 0.28209479177387814f;
    float d0 = C0c * sh[0], d1 = C0c * sh[1];

    // ---- view dirs + SH basis + scat ----
    float rx0 = g_rx[0], rx1 = g_rx[1], rx2 = g_rx[2];
    float dxw = rx0 - posx, dyw = rx1 - posy, dzw = rx2 - posz;
    float dnorm = sqrtf(dxw*dxw + dyw*dyw + dzw*dzw);
    float dinv = 1.f / fmaxf(dnorm, 1e-20f);
    float X = dxw * dinv, Yd = dyw * dinv, Z = dzw * dinv;
    float xx = X*X, yy = Yd*Yd, zz = Z*Z;
    float xy = X*Yd, yz = Yd*Z, xz = X*Z;
    float Yb[16];
    Yb[0]  = 0.28209479177387814f;
    Yb[1]  = -0.4886025119029199f * Yd;
    Yb[2]  =  0.4886025119029199f * Z;
    Yb[3]  = -0.4886025119029199f * X;
    Yb[4]  =  1.0925484305920792f * xy;
    Yb[5]  = -1.0925484305920792f * yz;
    Yb[6]  =  0.31539156525252005f * (2.f*zz - xx - yy);
    Yb[7]  = -1.0925484305920792f * xz;
    Yb[8]  =  0.5462742152960396f * (xx - yy);
    Yb[9]  = -0.5900435899266435f * Yd * (3.f*xx - yy);
    Yb[10] =  2.890611442640554f  * xy * Z;
    Yb[11] = -0.4570457994644658f * Yd * (4.f*zz - xx - yy);
    Yb[12] =  0.3731763325901154f * Z * (2.f*zz - 3.f*xx - 3.f*yy);
    Yb[13] = -0.4570457994644658f * X * (4.f*zz - xx - yy);
    Yb[14] =  1.445305721320277f  * Z * (xx - yy);
    Yb[15] = -0.5900435899266435f * X * (xx - 3.f*yy);

    int deg = g_deg[0];
    int nact = (deg + 1) * (deg + 1);
    float sc0 = 0.f, sc1 = 0.f;
#pragma unroll
    for (int c = 0; c < 16; ++c) {
        float yc = (c < nact) ? Yb[c] : 0.f;
        sc0 = fmaf(yc, sh[2*c+0], sc0);
        sc1 = fmaf(yc, sh[2*c+1], sc1);
    }

    float* op = g_out + (size_t)n * 39;
    __builtin_nontemporal_store(sel ? d0  : 0.f, op + 0);
    __builtin_nontemporal_store(sel ? d1  : 0.f, op + 1);
    __builtin_nontemporal_store(sel ? sc0 : 0.f, op + 2);
    __builtin_nontemporal_store(sel ? sc1 : 0.f, op + 3);
#pragma unroll
    for (int c = 0; c < 32; ++c)
        __builtin_nontemporal_store(sel ? sh[c] : 0.f, op + 7 + c);

    // ---- backward head: q = C0*d/|d| ----
    float ss = d0*d0 + d1*d1;
    float q0 = 0.f, q1 = 0.f;
    if (ss > 0.f) {
        float sr = sqrtf(ss);
        q0 = C0c * d0 / sr;
        q1 = C0c * d1 / sr;
    }
    float dzv[32];
#pragma unroll
    for (int i = 0; i < 32; ++i) {
        float dh = fmaf(q0, g_W2[i*32+0], q1 * g_W2[i*32+1]);
        dzv[i] = ((mask >> i) & 1u) ? dh : 0.f;
    }

    // ---- gradient: per level, da/db from W1 (L1-hit) x partials from ws ----
    // rolling prefetch: level l+1 partials issued before level l compute
    v4f c4 = __builtin_nontemporal_load(p4 + n);
    v2f c2 = __builtin_nontemporal_load(p2 + n);
    float gx = 0.f, gy = 0.f, gz = 0.f;
    const float4* w1v = (const float4*)g_W1;   // row r = w1v[r*8 .. r*8+7]
#pragma unroll
    for (int l = 0; l < NLV; ++l) {
        v4f n4 = c4; v2f n2 = c2;
        if (l + 1 < NLV) {
            n4 = __builtin_nontemporal_load(p4 + (size_t)(l+1) * N + n);
            n2 = __builtin_nontemporal_load(p2 + (size_t)(l+1) * N + n);
        }
        const float4* wa = w1v + (size_t)(2*l) * 8;
        const float4* wb = wa + 8;
        float da = 0.f, db = 0.f;
#pragma unroll
        for (int k = 0; k < 8; ++k) {
            float4 va = wa[k], vb = wb[k];
            da = fmaf(va.x, dzv[4*k+0], da);
            da = fmaf(va.y, dzv[4*k+1], da);
            da = fmaf(va.z, dzv[4*k+2], da);
            da = fmaf(va.w, dzv[4*k+3], da);
            db = fmaf(vb.x, dzv[4*k+0], db);
            db = fmaf(vb.y, dzv[4*k+1], db);
            db = fmaf(vb.z, dzv[4*k+2], db);
            db = fmaf(vb.w, dzv[4*k+3], db);
        }
        float res = rt.r[l];
        gx = fmaf(res, fmaf(da, c4.x, db * c4.y), gx);
        gy = fmaf(res, fmaf(da, c4.z, db * c4.w), gy);
        gz = fmaf(res, fmaf(da, c2.x, db * c2.y), gz);
        c4 = n4; c2 = n2;
    }

    // ---- world-space normal ----
    float gwx = gx / s0, gwy = gy / s1, gwz = gz / s2;
    float gn = sqrtf(gwx*gwx + gwy*gwy + gwz*gwz);
    float ginv = -1.f / fmaxf(gn, 1e-20f);
    __builtin_nontemporal_store(sel ? gwx * ginv : 0.f, op + 4);
    __builtin_nontemporal_store(sel ? gwy * ginv : 0.f, op + 5);
    __builtin_nontemporal_store(sel ? gwz * ginv : 0.f, op + 6);
}

// =====================================================================
// FALLBACK (round-7 fused kernel) if ws_size is too small.
// =====================================================================
__global__ __launch_bounds__(256, 2) void ngp_fused(
    const float* __restrict__ g_pos,
    const float* __restrict__ g_rx,
    const float* __restrict__ g_tab,
    const float* __restrict__ g_W1,
    const float* __restrict__ g_W2,
    const float* __restrict__ g_aabb,
    const int*   __restrict__ g_deg,
    float* __restrict__ g_out,
    int N, ResT rt)
{
    __shared__ float sm[48][256];

    int tid = blockIdx.x * 256 + threadIdx.x;
    int lt  = threadIdx.x;
    int n = tid >> 1;
    int p = tid & 1;
    if (n >= N) return;

    float posx = g_pos[3*n+0], posy = g_pos[3*n+1], posz = g_pos[3*n+2];
    float s0, s1, s2, pnx, pny, pnz; bool sel;
    aabb_norm(g_aabb, posx, posy, posz, s0, s1, s2, pnx, pny, pnz, sel);

    const float2* tab = (const float2*)g_tab;
    float f0o[8], f1o[8];
#pragma unroll
    for (int j = 0; j < 8; ++j) {
        float res = p ? rt.r[8+j] : rt.r[j];
        const float2* tl = tab + (size_t)(p * 8 + j) * TSZ;
        float fx = pnx * res, fy = pny * res, fz = pnz * res;
        float x0 = floorf(fx), y0 = floorf(fy), z0 = floorf(fz);
        float wx = fx - x0, wy = fy - y0, wz = fz - z0;
        float omx = 1.f - wx, omy = 1.f - wy, omz = 1.f - wz;
        unsigned ux = (unsigned)x0, uy = (unsigned)y0, uz = (unsigned)z0;
        unsigned hx0 = ux,        hx1 = ux + 1u;
        unsigned hy0 = uy * PR1,  hy1 = (uy + 1u) * PR1;
        unsigned hz0 = uz * PR2,  hz1 = (uz + 1u) * PR2;
        float f0 = 0.f, f1 = 0.f;
        float lxa = 0.f, lxb = 0.f, lya = 0.f, lyb = 0.f, lza = 0.f, lzb = 0.f;
#pragma unroll
        for (int c = 0; c < 8; ++c) {
            unsigned hh = ((c & 4) ? hx1 : hx0) ^ ((c & 2) ? hy1 : hy0) ^ ((c & 1) ? hz1 : hz0);
            float2 fv = tl[hh & TMASK];
            float wxv = (c & 4) ? wx : omx;
            float wyv = (c & 2) ? wy : omy;
            float wzv = (c & 1) ? wz : omz;
            float wgt = wxv * wyv;
            wgt = wgt * wzv;
            float t0 = fv.x * wgt;
            float t1 = fv.y * wgt;
            f0 = f0 + t0;
            f1 = f1 + t1;
            float pyz = wyv * wzv;
            float pxz = wxv * wzv;
            float pxy = wxv * wyv;
            float spx = (c & 4) ? pyz : -pyz;
            float spy = (c & 2) ? pxz : -pxz;
            float spz = (c & 1) ? pxy : -pxy;
            lxa = lxa + fv.x * spx;  lxb = lxb + fv.y * spx;
            lya = lya + fv.x * spy;  lyb = lyb + fv.y * spy;
            lza = lza + fv.x * spz;  lzb = lzb + fv.y * spz;
        }
        f0o[j] = f0; f1o[j] = f1;
        sm[j*6+0][lt] = lxa;  sm[j*6+1][lt] = lxb;
        sm[j*6+2][lt] = lya;  sm[j*6+3][lt] = lyb;
        sm[j*6+4][lt] = lza;  sm[j*6+5][lt] = lzb;
    }

    float z1[32];
#pragma unroll
    for (int i = 0; i < 32; ++i) z1[i] = 0.f;
    float hi0[8], hi1[8];
#pragma unroll
    for (int j = 0; j < 8; ++j) {
        float t0 = __shfl_xor(f0o[j], 1, 64);
        float t1 = __shfl_xor(f1o[j], 1, 64);
        float lo0 = p ? t0 : f0o[j];
        float lo1 = p ? t1 : f1o[j];
        hi0[j] = p ? f0o[j] : t0;
        hi1[j] = p ? f1o[j] : t1;
        const float* w1a = g_W1 + (2*j) * 32;
        const float* w1b = g_W1 + (2*j+1) * 32;
#pragma unroll
        for (int i = 0; i < 32; ++i) {
            float acc = fmaf(lo0, w1a[i], z1[i]);
            z1[i] = fmaf(lo1, w1b[i], acc);
        }
    }
#pragma unroll
    for (int j = 0; j < 8; ++j) {
        const float* w1a = g_W1 + (2*(8+j)) * 32;
        const float* w1b = g_W1 + (2*(8+j)+1) * 32;
#pragma unroll
        for (int i = 0; i < 32; ++i) {
            float acc = fmaf(hi0[j], w1a[i], z1[i]);
            z1[i] = fmaf(hi1[j], w1b[i], acc);
        }
    }

    unsigned mask = 0u;
    float sh[32];
#pragma unroll
    for (int o = 0; o < 32; ++o) sh[o] = 0.f;
#pragma unroll
    for (int i = 0; i < 32; ++i) {
        bool on = (z1[i] > 0.f);
        if (on) mask |= (1u << i);
        float h = on ? z1[i] : 0.f;
        const float* w2r = g_W2 + i * 32;
#pragma unroll
        for (int o = 0; o < 32; ++o) sh[o] = fmaf(h, w2r[o], sh[o]);
    }

    const float C0c = 0.28209479177387814f;
    float d0 = C0c * sh[0], d1 = C0c * sh[1];

    float rx0 = g_rx[0], rx1 = g_rx[1], rx2 = g_rx[2];
    float dxw = rx0 - posx, dyw = rx1 - posy, dzw = rx2 - posz;
    float dnorm = sqrtf(dxw*dxw + dyw*dyw + dzw*dzw);
    float dinv = 1.f / fmaxf(dnorm, 1e-20f);
    float X = dxw * dinv, Yd = dyw * dinv, Z = dzw * dinv;
    float xx = X*X, yy = Yd*Yd, zz = Z*Z;
    float xy = X*Yd, yz = Yd*Z, xz = X*Z;
    float Yb[16];
    Yb[0]  = 0.28209479177387814f;
    Yb[1]  = -0.4886025119029199f * Yd;
    Yb[2]  =  0.4886025119029199f * Z;
    Yb[3]  = -0.4886025119029199f * X;
    Yb[4]  =  1.0925484305920792f * xy;
    Yb[5]  = -1.0925484305920792f * yz;
    Yb[6]  =  0.31539156525252005f * (2.f*zz - xx - yy);
    Yb[7]  = -1.0925484305920792f * xz;
    Yb[8]  =  0.5462742152960396f * (xx - yy);
    Yb[9]  = -0.5900435899266435f * Yd * (3.f*xx - yy);
    Yb[10] =  2.890611442640554f  * xy * Z;
    Yb[11] = -0.4570457994644658f * Yd * (4.f*zz - xx - yy);
    Yb[12] =  0.3731763325901154f * Z * (2.f*zz - 3.f*xx - 3.f*yy);
    Yb[13] = -0.4570457994644658f * X * (4.f*zz - xx - yy);
    Yb[14] =  1.445305721320277f  * Z * (xx - yy);
    Yb[15] = -0.5900435899266435f * X * (xx - 3.f*yy);

    int deg = g_deg[0];
    int nact = (deg + 1) * (deg + 1);
    float sc0 = 0.f, sc1 = 0.f;
#pragma unroll
    for (int c = 0; c < 16; ++c) {
        float yc = (c < nact) ? Yb[c] : 0.f;
        sc0 = fmaf(yc, sh[2*c+0], sc0);
        sc1 = fmaf(yc, sh[2*c+1], sc1);
    }

    float* op = g_out + (size_t)n * 39;
    if (p == 0) {
        op[0] = sel ? d0  : 0.f;
        op[1] = sel ? d1  : 0.f;
        op[2] = sel ? sc0 : 0.f;
        op[3] = sel ? sc1 : 0.f;
#pragma unroll
        for (int c = 0; c < 13; ++c) op[7 + c] = sel ? sh[c] : 0.f;
    } else {
#pragma unroll
        for (int c = 13; c < 32; ++c) op[7 + c] = sel ? sh[c] : 0.f;
    }

    float ss = d0*d0 + d1*d1;
    float q0 = 0.f, q1 = 0.f;
    if (ss > 0.f) {
        float sr = sqrtf(ss);
        q0 = C0c * d0 / sr;
        q1 = C0c * d1 / sr;
    }
    float dzv[32];
#pragma unroll
    for (int i = 0; i < 32; ++i) {
        float dh = fmaf(q0, g_W2[i*32+0], q1 * g_W2[i*32+1]);
        dzv[i] = ((mask >> i) & 1u) ? dh : 0.f;
    }

    float gx = 0.f, gy = 0.f, gz = 0.f;
    const float4* w1v = (const float4*)g_W1;
    int rbase = p * 16;
#pragma unroll
    for (int j = 0; j < 8; ++j) {
        const float4* wa = w1v + (size_t)(rbase + 2*j) * 8;
        const float4* wb = wa + 8;
        float da = 0.f, db = 0.f;
#pragma unroll
        for (int k = 0; k < 8; ++k) {
            float4 va = wa[k], vb = wb[k];
            da = fmaf(va.x, dzv[4*k+0], da);
            da = fmaf(va.y, dzv[4*k+1], da);
            da = fmaf(va.z, dzv[4*k+2], da);
            da = fmaf(va.w, dzv[4*k+3], da);
            db = fmaf(vb.x, dzv[4*k+0], db);
            db = fmaf(vb.y, dzv[4*k+1], db);
            db = fmaf(vb.z, dzv[4*k+2], db);
            db = fmaf(vb.w, dzv[4*k+3], db);
        }
        float xa = sm[j*6+0][lt], xb = sm[j*6+1][lt];
        float ya = sm[j*6+2][lt], yb = sm[j*6+3][lt];
        float za = sm[j*6+4][lt], zb = sm[j*6+5][lt];
        float res = p ? rt.r[8+j] : rt.r[j];
        gx = fmaf(res, fmaf(da, xa, db * xb), gx);
        gy = fmaf(res, fmaf(da, ya, db * yb), gy);
        gz = fmaf(res, fmaf(da, za, db * zb), gz);
    }
    float tx = __shfl_xor(gx, 1, 64);
    float ty = __shfl_xor(gy, 1, 64);
    float tz = __shfl_xor(gz, 1, 64);
    gx = gx + tx; gy = gy + ty; gz = gz + tz;

    float gwx = gx / s0, gwy = gy / s1, gwz = gz / s2;
    float gn = sqrtf(gwx*gwx + gwy*gwy + gwz*gwz);
    float ginv = -1.f / fmaxf(gn, 1e-20f);
    if (p == 0) {
        op[4] = sel ? gwx * ginv : 0.f;
        op[5] = sel ? gwy * ginv : 0.f;
        op[6] = sel ? gwz * ginv : 0.f;
    }
}

extern "C" void kernel_launch(void* const* d_in, const int* in_sizes, int n_in,
                              void* d_out, int out_size, void* d_ws, size_t ws_size,
                              hipStream_t stream)
{
    const float* g_pos  = (const float*)d_in[0];
    const float* g_rx   = (const float*)d_in[1];
    const float* g_tab  = (const float*)d_in[2];
    const float* g_W1   = (const float*)d_in[3];
    const float* g_W2   = (const float*)d_in[4];
    const float* g_aabb = (const float*)d_in[5];
    const int*   g_deg  = (const int*)d_in[6];
    float* g_out = (float*)d_out;

    int N = in_sizes[0] / 3;

    // RES exactly as the reference: python float64 exp/log/pow, cast to fp32.
    ResT rt;
    double scale = exp((log(4096.0) - log(16.0)) / 15.0);
    for (int l = 0; l < NLV; ++l) rt.r[l] = (float)(16.0 * pow(scale, (double)l));

    size_t need = (size_t)NLV * N * 8 * sizeof(float);   // 134 MB at N=262144
    if (ws_size >= need) {
        float* ws = (float*)d_ws;
        int chunks = (N + 255) / 256;
        level_gather<<<NLV * chunks, 256, 0, stream>>>(g_pos, g_tab, g_aabb,
                                                       ws, N, chunks, rt);
        mlp_bwd<<<chunks, 256, 0, stream>>>(g_pos, g_rx, g_W1, g_W2, g_aabb,
                                            g_deg, ws, g_out, N, rt);
    } else {
        long long threads = 2LL * N;
        int blocks = (int)((threads + 255) / 256);
        ngp_fused<<<blocks, 256, 0, stream>>>(g_pos, g_rx, g_tab, g_W1, g_W2,
                                              g_aabb, g_deg, g_out, N, rt);
    }
}

// Round 2
// 381.838 us; speedup vs baseline: 1.0298x; 1.0298x over previous
//
#include <hip/hip_runtime.h>
#include <cmath>

// Forbid FMA contraction: the reference check is a float32 numpy replay with
// individually-rounded ops. We opt into FMA explicitly (fmaf) only where
// BLAS sgemm itself uses an FMA chain.
#pragma clang fp contract(off)

#define NLV 16
#define TSZ (1u << 19)
#define TMASK (TSZ - 1u)
#define PR1 2654435761u
#define PR2 805459861u

typedef float v2f __attribute__((ext_vector_type(2)));
typedef float v4f __attribute__((ext_vector_type(4)));

struct ResT { float r[NLV]; };

// ---------- shared helpers (bit-exact fp32, matches np reference) ----------
__device__ __forceinline__ void aabb_norm(
    const float* __restrict__ g_aabb, float posx, float posy, float posz,
    float& s0, float& s1, float& s2,
    float& pnx, float& pny, float& pnz, bool& sel)
{
    float a0 = g_aabb[0], a1 = g_aabb[1], a2 = g_aabb[2];
    s0 = fmaxf(g_aabb[3] - a0, 1e-6f);
    s1 = fmaxf(g_aabb[4] - a1, 1e-6f);
    s2 = fmaxf(g_aabb[5] - a2, 1e-6f);
    float nx = (posx - a0) / s0;
    float ny = (posy - a1) / s1;
    float nz = (posz - a2) / s2;
    sel = (nx >= 0.f) && (nx <= 1.f) && (ny >= 0.f) && (ny <= 1.f)
       && (nz >= 0.f) && (nz <= 1.f);
    pnx = fminf(fmaxf(nx, 0.f), 1.f);
    pny = fminf(fmaxf(ny, 0.f), 1.f);
    pnz = fminf(fmaxf(nz, 0.f), 1.f);
}

// =====================================================================
// PASS A: one (point, level) per thread.
// LEVEL-MAJOR ORDER: lvl = b / chunks, so at any instant ALL 8 XCDs work
// on the SAME level (block->XCD is round-robin on blockIdx). Each XCD's
// L2 holds its own copy of the active 4 MB table slice (8x4MB, fits),
// the level's random gathers are served by 8 L2s instead of 1, and the
// load is perfectly balanced (every XCD does 1/8 of every level).
// Round-1's (l, l+8)-per-XCD pairing left XCDs 5-7 with two full-random
// levels each = 2x the L2 request work of XCD 0 -> 171 us critical path.
// ws stores are PLAIN (cached): round-1's nontemporal stores pushed ws
// out of L3 and cost pass B ~70 us of extra latency per load.
// ws layout packed for pass B:
//   f2[l*N+n]  = (f0,f1)           (v2f plane)
//   p4[l*N+n]  = (xa,xb,ya,yb)     (v4f plane)
//   p2[l*N+n]  = (za,zb)           (v2f plane)
// =====================================================================
__global__ __launch_bounds__(256) void level_gather(
    const float* __restrict__ g_pos,
    const float* __restrict__ g_tab,
    const float* __restrict__ g_aabb,
    float* __restrict__ ws,
    int N, int chunks, ResT rt)
{
    int b = blockIdx.x;
    int lvl = b / chunks;                      // level-major
    int n = (b - lvl * chunks) * 256 + threadIdx.x;
    if (n >= N) return;

    float posx = g_pos[3*n+0], posy = g_pos[3*n+1], posz = g_pos[3*n+2];
    float s0, s1, s2, pnx, pny, pnz; bool sel;
    aabb_norm(g_aabb, posx, posy, posz, s0, s1, s2, pnx, pny, pnz, sel);

    float res = rt.r[lvl];                       // wave-uniform scalar
    const float2* tl = (const float2*)g_tab + (size_t)lvl * TSZ;

    float fx = pnx * res, fy = pny * res, fz = pnz * res;
    float x0 = floorf(fx), y0 = floorf(fy), z0 = floorf(fz);
    float wx = fx - x0, wy = fy - y0, wz = fz - z0;
    float omx = 1.f - wx, omy = 1.f - wy, omz = 1.f - wz;
    unsigned ux = (unsigned)x0, uy = (unsigned)y0, uz = (unsigned)z0;
    unsigned hx0 = ux,        hx1 = ux + 1u;
    unsigned hy0 = uy * PR1,  hy1 = (uy + 1u) * PR1;
    unsigned hz0 = uz * PR2,  hz1 = (uz + 1u) * PR2;
    float f0 = 0.f, f1 = 0.f;
    float lxa = 0.f, lxb = 0.f, lya = 0.f, lyb = 0.f, lza = 0.f, lzb = 0.f;
#pragma unroll
    for (int c = 0; c < 8; ++c) {
        unsigned hh = ((c & 4) ? hx1 : hx0) ^ ((c & 2) ? hy1 : hy0) ^ ((c & 1) ? hz1 : hz0);
        float2 fv = tl[hh & TMASK];
        float wxv = (c & 4) ? wx : omx;
        float wyv = (c & 2) ? wy : omy;
        float wzv = (c & 1) ? wz : omz;
        // forward: wc = (x*y)*z, each op rounded; f += fv*wc seq c=0..7
        float wgt = wxv * wyv;
        wgt = wgt * wzv;
        float t0 = fv.x * wgt;
        float t1 = fv.y * wgt;
        f0 = f0 + t0;
        f1 = f1 + t1;
        // gradient partials (sign flip by corner bit is exact)
        float pyz = wyv * wzv;
        float pxz = wxv * wzv;
        float pxy = wxv * wyv;
        float spx = (c & 4) ? pyz : -pyz;
        float spy = (c & 2) ? pxz : -pxz;
        float spz = (c & 1) ? pxy : -pxy;
        lxa = lxa + fv.x * spx;  lxb = lxb + fv.y * spx;
        lya = lya + fv.x * spy;  lyb = lyb + fv.y * spy;
        lza = lza + fv.x * spz;  lzb = lzb + fv.y * spz;
    }

    size_t LN = (size_t)NLV * N;
    size_t idx = (size_t)lvl * N + n;
    v2f* f2 = (v2f*)ws;                  // 2*LN floats
    v4f* p4 = (v4f*)(ws + 2*LN);         // 4*LN floats
    v2f* p2 = (v2f*)(ws + 6*LN);         // 2*LN floats
    v2f ff = {f0, f1};
    v4f pa = {lxa, lxb, lya, lyb};
    v2f pz = {lza, lzb};
    f2[idx] = ff;
    p4[idx] = pa;
    p2[idx] = pz;
}

// =====================================================================
// PASS B: one thread per point. No table access; streams f/partials
// from workspace (plain cached loads — ws is L3-resident after pass A),
// replays the exact reference z1/sh chain, backward. Round-0 structure
// (no prefetch-all, no forced unroll — kept VGPRs low and hit 152 us);
// only change: packed v2f/v4f planes cut ws requests 128 -> 48/thread.
// =====================================================================
__global__ __launch_bounds__(256) void mlp_bwd(
    const float* __restrict__ g_pos,
    const float* __restrict__ g_rx,
    const float* __restrict__ g_W1,
    const float* __restrict__ g_W2,
    const float* __restrict__ g_aabb,
    const int*   __restrict__ g_deg,
    const float* __restrict__ ws,
    float* __restrict__ g_out,
    int N, ResT rt)
{
    int n = blockIdx.x * 256 + threadIdx.x;
    if (n >= N) return;

    float posx = g_pos[3*n+0], posy = g_pos[3*n+1], posz = g_pos[3*n+2];
    float s0, s1, s2, pnx, pny, pnz; bool sel;
    aabb_norm(g_aabb, posx, posy, posz, s0, s1, s2, pnx, pny, pnz, sel);
    (void)pnx; (void)pny; (void)pnz;

    size_t LN = (size_t)NLV * N;
    const v2f* f2 = (const v2f*)ws;
    const v4f* p4 = (const v4f*)(ws + 2*LN);
    const v2f* p2 = (const v2f*)(ws + 6*LN);

    // ---- z1 = feats@W1, exact level order, sgemm FMA chain ascending k ----
    float z1[32];
#pragma unroll
    for (int i = 0; i < 32; ++i) z1[i] = 0.f;
    for (int l = 0; l < NLV; ++l) {
        v2f fv = f2[(size_t)l * N + n];
        float f0 = fv.x;
        float f1 = fv.y;
        const float* w1a = g_W1 + (2*l) * 32;
        const float* w1b = g_W1 + (2*l+1) * 32;
#pragma unroll
        for (int i = 0; i < 32; ++i) {
            float acc = fmaf(f0, w1a[i], z1[i]);   // k=2l then k=2l+1
            z1[i] = fmaf(f1, w1b[i], acc);
        }
    }

    // ---- relu + second layer (sgemm FMA chain, ascending j) ----
    unsigned mask = 0u;
    float sh[32];
#pragma unroll
    for (int o = 0; o < 32; ++o) sh[o] = 0.f;
#pragma unroll
    for (int i = 0; i < 32; ++i) {
        bool on = (z1[i] > 0.f);
        if (on) mask |= (1u << i);
        float h = on ? z1[i] : 0.f;
        const float* w2r = g_W2 + i * 32;
#pragma unroll
        for (int o = 0; o < 32; ++o) sh[o] = fmaf(h, w2r[o], sh[o]);
    }

    const float C0c = 0.28209479177387814f;
    float d0 = C0c * sh[0], d1 = C0c * sh[1];

    // ---- view dirs + SH basis + scat ----
    float rx0 = g_rx[0], rx1 = g_rx[1], rx2 = g_rx[2];
    float dxw = rx0 - posx, dyw = rx1 - posy, dzw = rx2 - posz;
    float dnorm = sqrtf(dxw*dxw + dyw*dyw + dzw*dzw);
    float dinv = 1.f / fmaxf(dnorm, 1e-20f);
    float X = dxw * dinv, Yd = dyw * dinv, Z = dzw * dinv;
    float xx = X*X, yy = Yd*Yd, zz = Z*Z;
    float xy = X*Yd, yz = Yd*Z, xz = X*Z;
    float Yb[16];
    Yb[0]  = 0.28209479177387814f;
    Yb[1]  = -0.4886025119029199f * Yd;
    Yb[2]  =  0.4886025119029199f * Z;
    Yb[3]  = -0.4886025119029199f * X;
    Yb[4]  =  1.0925484305920792f * xy;
    Yb[5]  = -1.0925484305920792f * yz;
    Yb[6]  =  0.31539156525252005f * (2.f*zz - xx - yy);
    Yb[7]  = -1.0925484305920792f * xz;
    Yb[8]  =  0.5462742152960396f * (xx - yy);
    Yb[9]  = -0.5900435899266435f * Yd * (3.f*xx - yy);
    Yb[10] =  2.890611442640554f  * xy * Z;
    Yb[11] = -0.4570457994644658f * Yd * (4.f*zz - xx - yy);
    Yb[12] =  0.3731763325901154f * Z * (2.f*zz - 3.f*xx - 3.f*yy);
    Yb[13] = -0.4570457994644658f * X * (4.f*zz - xx - yy);
    Yb[14] =  1.445305721320277f  * Z * (xx - yy);
    Yb[15] = -0.5900435899266435f * X * (xx - 3.f*yy);

    int deg = g_deg[0];
    int nact = (deg + 1) * (deg + 1);
    float sc0 = 0.f, sc1 = 0.f;
#pragma unroll
    for (int c = 0; c < 16; ++c) {
        float yc = (c < nact) ? Yb[c] : 0.f;
        sc0 = fmaf(yc, sh[2*c+0], sc0);
        sc1 = fmaf(yc, sh[2*c+1], sc1);
    }

    float* op = g_out + (size_t)n * 39;
    op[0] = sel ? d0  : 0.f;
    op[1] = sel ? d1  : 0.f;
    op[2] = sel ? sc0 : 0.f;
    op[3] = sel ? sc1 : 0.f;
#pragma unroll
    for (int c = 0; c < 32; ++c) op[7 + c] = sel ? sh[c] : 0.f;

    // ---- backward head: q = C0*d/|d| ----
    float ss = d0*d0 + d1*d1;
    float q0 = 0.f, q1 = 0.f;
    if (ss > 0.f) {
        float sr = sqrtf(ss);
        q0 = C0c * d0 / sr;
        q1 = C0c * d1 / sr;
    }
    float dzv[32];
#pragma unroll
    for (int i = 0; i < 32; ++i) {
        float dh = fmaf(q0, g_W2[i*32+0], q1 * g_W2[i*32+1]);
        dzv[i] = ((mask >> i) & 1u) ? dh : 0.f;
    }

    // ---- gradient: per level, da/db from W1 (L1-hit) x partials from ws ----
    float gx = 0.f, gy = 0.f, gz = 0.f;
    const float4* w1v = (const float4*)g_W1;   // row r = w1v[r*8 .. r*8+7]
    for (int l = 0; l < NLV; ++l) {
        // issue the two ws loads first; 32 fmafs below hide their latency
        v4f c4 = p4[(size_t)l * N + n];
        v2f c2 = p2[(size_t)l * N + n];
        const float4* wa = w1v + (size_t)(2*l) * 8;
        const float4* wb = wa + 8;
        float da = 0.f, db = 0.f;
#pragma unroll
        for (int k = 0; k < 8; ++k) {
            float4 va = wa[k], vb = wb[k];
            da = fmaf(va.x, dzv[4*k+0], da);
            da = fmaf(va.y, dzv[4*k+1], da);
            da = fmaf(va.z, dzv[4*k+2], da);
            da = fmaf(va.w, dzv[4*k+3], da);
            db = fmaf(vb.x, dzv[4*k+0], db);
            db = fmaf(vb.y, dzv[4*k+1], db);
            db = fmaf(vb.z, dzv[4*k+2], db);
            db = fmaf(vb.w, dzv[4*k+3], db);
        }
        float res = rt.r[l];
        gx = fmaf(res, fmaf(da, c4.x, db * c4.y), gx);
        gy = fmaf(res, fmaf(da, c4.z, db * c4.w), gy);
        gz = fmaf(res, fmaf(da, c2.x, db * c2.y), gz);
    }

    // ---- world-space normal ----
    float gwx = gx / s0, gwy = gy / s1, gwz = gz / s2;
    float gn = sqrtf(gwx*gwx + gwy*gwy + gwz*gwz);
    float ginv = -1.f / fmaxf(gn, 1e-20f);
    op[4] = sel ? gwx * ginv : 0.f;
    op[5] = sel ? gwy * ginv : 0.f;
    op[6] = sel ? gwz * ginv : 0.f;
}

// =====================================================================
// FALLBACK (round-7 fused kernel) if ws_size is too small.
// =====================================================================
__global__ __launch_bounds__(256, 2) void ngp_fused(
    const float* __restrict__ g_pos,
    const float* __restrict__ g_rx,
    const float* __restrict__ g_tab,
    const float* __restrict__ g_W1,
    const float* __restrict__ g_W2,
    const float* __restrict__ g_aabb,
    const int*   __restrict__ g_deg,
    float* __restrict__ g_out,
    int N, ResT rt)
{
    __shared__ float sm[48][256];

    int tid = blockIdx.x * 256 + threadIdx.x;
    int lt  = threadIdx.x;
    int n = tid >> 1;
    int p = tid & 1;
    if (n >= N) return;

    float posx = g_pos[3*n+0], posy = g_pos[3*n+1], posz = g_pos[3*n+2];
    float s0, s1, s2, pnx, pny, pnz; bool sel;
    aabb_norm(g_aabb, posx, posy, posz, s0, s1, s2, pnx, pny, pnz, sel);

    const float2* tab = (const float2*)g_tab;
    float f0o[8], f1o[8];
#pragma unroll
    for (int j = 0; j < 8; ++j) {
        float res = p ? rt.r[8+j] : rt.r[j];
        const float2* tl = tab + (size_t)(p * 8 + j) * TSZ;
        float fx = pnx * res, fy = pny * res, fz = pnz * res;
        float x0 = floorf(fx), y0 = floorf(fy), z0 = floorf(fz);
        float wx = fx - x0, wy = fy - y0, wz = fz - z0;
        float omx = 1.f - wx, omy = 1.f - wy, omz = 1.f - wz;
        unsigned ux = (unsigned)x0, uy = (unsigned)y0, uz = (unsigned)z0;
        unsigned hx0 = ux,        hx1 = ux + 1u;
        unsigned hy0 = uy * PR1,  hy1 = (uy + 1u) * PR1;
        unsigned hz0 = uz * PR2,  hz1 = (uz + 1u) * PR2;
        float f0 = 0.f, f1 = 0.f;
        float lxa = 0.f, lxb = 0.f, lya = 0.f, lyb = 0.f, lza = 0.f, lzb = 0.f;
#pragma unroll
        for (int c = 0; c < 8; ++c) {
            unsigned hh = ((c & 4) ? hx1 : hx0) ^ ((c & 2) ? hy1 : hy0) ^ ((c & 1) ? hz1 : hz0);
            float2 fv = tl[hh & TMASK];
            float wxv = (c & 4) ? wx : omx;
            float wyv = (c & 2) ? wy : omy;
            float wzv = (c & 1) ? wz : omz;
            float wgt = wxv * wyv;
            wgt = wgt * wzv;
            float t0 = fv.x * wgt;
            float t1 = fv.y * wgt;
            f0 = f0 + t0;
            f1 = f1 + t1;
            float pyz = wyv * wzv;
            float pxz = wxv * wzv;
            float pxy = wxv * wyv;
            float spx = (c & 4) ? pyz : -pyz;
            float spy = (c & 2) ? pxz : -pxz;
            float spz = (c & 1) ? pxy : -pxy;
            lxa = lxa + fv.x * spx;  lxb = lxb + fv.y * spx;
            lya = lya + fv.x * spy;  lyb = lyb + fv.y * spy;
            lza = lza + fv.x * spz;  lzb = lzb + fv.y * spz;
        }
        f0o[j] = f0; f1o[j] = f1;
        sm[j*6+0][lt] = lxa;  sm[j*6+1][lt] = lxb;
        sm[j*6+2][lt] = lya;  sm[j*6+3][lt] = lyb;
        sm[j*6+4][lt] = lza;  sm[j*6+5][lt] = lzb;
    }

    float z1[32];
#pragma unroll
    for (int i = 0; i < 32; ++i) z1[i] = 0.f;
    float hi0[8], hi1[8];
#pragma unroll
    for (int j = 0; j < 8; ++j) {
        float t0 = __shfl_xor(f0o[j], 1, 64);
        float t1 = __shfl_xor(f1o[j], 1, 64);
        float lo0 = p ? t0 : f0o[j];
        float lo1 = p ? t1 : f1o[j];
        hi0[j] = p ? f0o[j] : t0;
        hi1[j] = p ? f1o[j] : t1;
        const float* w1a = g_W1 + (2*j) * 32;
        const float* w1b = g_W1 + (2*j+1) * 32;
#pragma unroll
        for (int i = 0; i < 32; ++i) {
            float acc = fmaf(lo0, w1a[i], z1[i]);
            z1[i] = fmaf(lo1, w1b[i], acc);
        }
    }
#pragma unroll
    for (int j = 0; j < 8; ++j) {
        const float* w1a = g_W1 + (2*(8+j)) * 32;
        const float* w1b = g_W1 + (2*(8+j)+1) * 32;
#pragma unroll
        for (int i = 0; i < 32; ++i) {
            float acc = fmaf(hi0[j], w1a[i], z1[i]);
            z1[i] = fmaf(hi1[j], w1b[i], acc);
        }
    }

    unsigned mask = 0u;
    float sh[32];
#pragma unroll
    for (int o = 0; o < 32; ++o) sh[o] = 0.f;
#pragma unroll
    for (int i = 0; i < 32; ++i) {
        bool on = (z1[i] > 0.f);
        if (on) mask |= (1u << i);
        float h = on ? z1[i] : 0.f;
        const float* w2r = g_W2 + i * 32;
#pragma unroll
        for (int o = 0; o < 32; ++o) sh[o] = fmaf(h, w2r[o], sh[o]);
    }

    const float C0c = 0.28209479177387814f;
    float d0 = C0c * sh[0], d1 = C0c * sh[1];

    float rx0 = g_rx[0], rx1 = g_rx[1], rx2 = g_rx[2];
    float dxw = rx0 - posx, dyw = rx1 - posy, dzw = rx2 - posz;
    float dnorm = sqrtf(dxw*dxw + dyw*dyw + dzw*dzw);
    float dinv = 1.f / fmaxf(dnorm, 1e-20f);
    float X = dxw * dinv, Yd = dyw * dinv, Z = dzw * dinv;
    float xx = X*X, yy = Yd*Yd, zz = Z*Z;
    float xy = X*Yd, yz = Yd*Z, xz = X*Z;
    float Yb[16];
    Yb[0]  = 0.28209479177387814f;
    Yb[1]  = -0.4886025119029199f * Yd;
    Yb[2]  =  0.4886025119029199f * Z;
    Yb[3]  = -0.4886025119029199f * X;
    Yb[4]  =  1.0925484305920792f * xy;
    Yb[5]  = -1.0925484305920792f * yz;
    Yb[6]  =  0.31539156525252005f * (2.f*zz - xx - yy);
    Yb[7]  = -1.0925484305920792f * xz;
    Yb[8]  =  0.5462742152960396f * (xx - yy);
    Yb[9]  = -0.5900435899266435f * Yd * (3.f*xx - yy);
    Yb[10] =  2.890611442640554f  * xy * Z;
    Yb[11] = -0.4570457994644658f * Yd * (4.f*zz - xx - yy);
    Yb[12] =  0.3731763325901154f * Z * (2.f*zz - 3.f*xx - 3.f*yy);
    Yb[13] = -0.4570457994644658f * X * (4.f*zz - xx - yy);
    Yb[14] =  1.445305721320277f  * Z * (xx - yy);
    Yb[15] = -0.5900435899266435f * X * (xx - 3.f*yy);

    int deg = g_deg[0];
    int nact = (deg + 1) * (deg + 1);
    float sc0 = 0.f, sc1 = 0.f;
#pragma unroll
    for (int c = 0; c < 16; ++c) {
        float yc = (c < nact) ? Yb[c] : 0.f;
        sc0 = fmaf(yc, sh[2*c+0], sc0);
        sc1 = fmaf(yc, sh[2*c+1], sc1);
    }

    float* op = g_out + (size_t)n * 39;
    if (p == 0) {
        op[0] = sel ? d0  : 0.f;
        op[1] = sel ? d1  : 0.f;
        op[2] = sel ? sc0 : 0.f;
        op[3] = sel ? sc1 : 0.f;
#pragma unroll
        for (int c = 0; c < 13; ++c) op[7 + c] = sel ? sh[c] : 0.f;
    } else {
#pragma unroll
        for (int c = 13; c < 32; ++c) op[7 + c] = sel ? sh[c] : 0.f;
    }

    float ss = d0*d0 + d1*d1;
    float q0 = 0.f, q1 = 0.f;
    if (ss > 0.f) {
        float sr = sqrtf(ss);
        q0 = C0c * d0 / sr;
        q1 = C0c * d1 / sr;
    }
    float dzv[32];
#pragma unroll
    for (int i = 0; i < 32; ++i) {
        float dh = fmaf(q0, g_W2[i*32+0], q1 * g_W2[i*32+1]);
        dzv[i] = ((mask >> i) & 1u) ? dh : 0.f;
    }

    float gx = 0.f, gy = 0.f, gz = 0.f;
    const float4* w1v = (const float4*)g_W1;
    int rbase = p * 16;
#pragma unroll
    for (int j = 0; j < 8; ++j) {
        const float4* wa = w1v + (size_t)(rbase + 2*j) * 8;
        const float4* wb = wa + 8;
        float da = 0.f, db = 0.f;
#pragma unroll
        for (int k = 0; k < 8; ++k) {
            float4 va = wa[k], vb = wb[k];
            da = fmaf(va.x, dzv[4*k+0], da);
            da = fmaf(va.y, dzv[4*k+1], da);
            da = fmaf(va.z, dzv[4*k+2], da);
            da = fmaf(va.w, dzv[4*k+3], da);
            db = fmaf(vb.x, dzv[4*k+0], db);
            db = fmaf(vb.y, dzv[4*k+1], db);
            db = fmaf(vb.z, dzv[4*k+2], db);
            db = fmaf(vb.w, dzv[4*k+3], db);
        }
        float xa = sm[j*6+0][lt], xb = sm[j*6+1][lt];
        float ya = sm[j*6+2][lt], yb = sm[j*6+3][lt];
        float za = sm[j*6+4][lt], zb = sm[j*6+5][lt];
        float res = p ? rt.r[8+j] : rt.r[j];
        gx = fmaf(res, fmaf(da, xa, db * xb), gx);
        gy = fmaf(res, fmaf(da, ya, db * yb), gy);
        gz = fmaf(res, fmaf(da, za, db * zb), gz);
    }
    float tx = __shfl_xor(gx, 1, 64);
    float ty = __shfl_xor(gy, 1, 64);
    float tz = __shfl_xor(gz, 1, 64);
    gx = gx + tx; gy = gy + ty; gz = gz + tz;

    float gwx = gx / s0, gwy = gy / s1, gwz = gz / s2;
    float gn = sqrtf(gwx*gwx + gwy*gwy + gwz*gwz);
    float ginv = -1.f / fmaxf(gn, 1e-20f);
    if (p == 0) {
        op[4] = sel ? gwx * ginv : 0.f;
        op[5] = sel ? gwy * ginv : 0.f;
        op[6] = sel ? gwz * ginv : 0.f;
    }
}

extern "C" void kernel_launch(void* const* d_in, const int* in_sizes, int n_in,
                              void* d_out, int out_size, void* d_ws, size_t ws_size,
                              hipStream_t stream)
{
    const float* g_pos  = (const float*)d_in[0];
    const float* g_rx   = (const float*)d_in[1];
    const float* g_tab  = (const float*)d_in[2];
    const float* g_W1   = (const float*)d_in[3];
    const float* g_W2   = (const float*)d_in[4];
    const float* g_aabb = (const float*)d_in[5];
    const int*   g_deg  = (const int*)d_in[6];
    float* g_out = (float*)d_out;

    int N = in_sizes[0] / 3;

    // RES exactly as the reference: python float64 exp/log/pow, cast to fp32.
    ResT rt;
    double scale = exp((log(4096.0) - log(16.0)) / 15.0);
    for (int l = 0; l < NLV; ++l) rt.r[l] = (float)(16.0 * pow(scale, (double)l));

    size_t need = (size_t)NLV * N * 8 * sizeof(float);   // 134 MB at N=262144
    if (ws_size >= need) {
        float* ws = (float*)d_ws;
        int chunks = (N + 255) / 256;
        level_gather<<<NLV * chunks, 256, 0, stream>>>(g_pos, g_tab, g_aabb,
                                                       ws, N, chunks, rt);
        mlp_bwd<<<chunks, 256, 0, stream>>>(g_pos, g_rx, g_W1, g_W2, g_aabb,
                                            g_deg, ws, g_out, N, rt);
    } else {
        long long threads = 2LL * N;
        int blocks = (int)((threads + 255) / 256);
        ngp_fused<<<blocks, 256, 0, stream>>>(g_pos, g_rx, g_tab, g_W1, g_W2,
                                              g_aabb, g_deg, g_out, N, rt);
    }
}

// Round 3
// 335.434 us; speedup vs baseline: 1.1722x; 1.1383x over previous
//
#include <hip/hip_runtime.h>
#include <cmath>

// Forbid FMA contraction: the reference check is a float32 numpy replay with
// individually-rounded ops. We opt into FMA explicitly (fmaf) only where
// BLAS sgemm itself uses an FMA chain.
#pragma clang fp contract(off)

#define NLV 16
#define TSZ (1u << 19)
#define TMASK (TSZ - 1u)
#define PR1 2654435761u
#define PR2 805459861u

typedef float v2f __attribute__((ext_vector_type(2)));
typedef float v4f __attribute__((ext_vector_type(4)));

struct ResT { float r[NLV]; };

// ---------- shared helpers (bit-exact fp32, matches np reference) ----------
__device__ __forceinline__ void aabb_norm(
    const float* __restrict__ g_aabb, float posx, float posy, float posz,
    float& s0, float& s1, float& s2,
    float& pnx, float& pny, float& pnz, bool& sel)
{
    float a0 = g_aabb[0], a1 = g_aabb[1], a2 = g_aabb[2];
    s0 = fmaxf(g_aabb[3] - a0, 1e-6f);
    s1 = fmaxf(g_aabb[4] - a1, 1e-6f);
    s2 = fmaxf(g_aabb[5] - a2, 1e-6f);
    float nx = (posx - a0) / s0;
    float ny = (posy - a1) / s1;
    float nz = (posz - a2) / s2;
    sel = (nx >= 0.f) && (nx <= 1.f) && (ny >= 0.f) && (ny <= 1.f)
       && (nz >= 0.f) && (nz <= 1.f);
    pnx = fminf(fmaxf(nx, 0.f), 1.f);
    pny = fminf(fmaxf(ny, 0.f), 1.f);
    pnz = fminf(fmaxf(nz, 0.f), 1.f);
}

// =====================================================================
// PASS A: one (point, level) per thread. ROUND-1 MAPPING (measured best,
// 171 us, FETCH 95 MB): two time phases; phase 0 runs levels 0..7 with
// level l pinned to XCD l (b%8 round-robin), phase 1 runs levels 8..15.
// Each XCD holds exactly ONE 4 MB slice at a time -> slice L2-resident.
// Request-count per XCD is total/8 regardless of mapping (4.2 M random
// 8B gathers), and measured 171 us = 10.2 req/cyc/XCD = the L2 random-
// request throughput ceiling — this pass is at its structural floor.
// ws stores NON-TEMPORAL: keeps the 131 MB stream from evicting the
// pinned slice out of L2 (memory-side L3 still absorbs the writes, so
// pass B's plain loads hit L3).
// ws layout packed for pass B:
//   f2[l*N+n]  = (f0,f1)           (v2f plane)
//   p4[l*N+n]  = (xa,xb,ya,yb)     (v4f plane)
//   p2[l*N+n]  = (za,zb)           (v2f plane)
// =====================================================================
__global__ __launch_bounds__(256) void level_gather(
    const float* __restrict__ g_pos,
    const float* __restrict__ g_tab,
    const float* __restrict__ g_aabb,
    float* __restrict__ ws,
    int N, int chunks, ResT rt)
{
    int b = blockIdx.x;
    int half = (b >= 8 * chunks) ? 1 : 0;
    int bb = b - half * (8 * chunks);
    int lvl = (bb & 7) + (half << 3);
    int n = (bb >> 3) * 256 + threadIdx.x;
    if (n >= N) return;

    float posx = g_pos[3*n+0], posy = g_pos[3*n+1], posz = g_pos[3*n+2];
    float s0, s1, s2, pnx, pny, pnz; bool sel;
    aabb_norm(g_aabb, posx, posy, posz, s0, s1, s2, pnx, pny, pnz, sel);

    float res = rt.r[lvl];                       // wave-uniform scalar
    const float2* tl = (const float2*)g_tab + (size_t)lvl * TSZ;

    float fx = pnx * res, fy = pny * res, fz = pnz * res;
    float x0 = floorf(fx), y0 = floorf(fy), z0 = floorf(fz);
    float wx = fx - x0, wy = fy - y0, wz = fz - z0;
    float omx = 1.f - wx, omy = 1.f - wy, omz = 1.f - wz;
    unsigned ux = (unsigned)x0, uy = (unsigned)y0, uz = (unsigned)z0;
    unsigned hx0 = ux,        hx1 = ux + 1u;
    unsigned hy0 = uy * PR1,  hy1 = (uy + 1u) * PR1;
    unsigned hz0 = uz * PR2,  hz1 = (uz + 1u) * PR2;
    float f0 = 0.f, f1 = 0.f;
    float lxa = 0.f, lxb = 0.f, lya = 0.f, lyb = 0.f, lza = 0.f, lzb = 0.f;
#pragma unroll
    for (int c = 0; c < 8; ++c) {
        unsigned hh = ((c & 4) ? hx1 : hx0) ^ ((c & 2) ? hy1 : hy0) ^ ((c & 1) ? hz1 : hz0);
        float2 fv = tl[hh & TMASK];
        float wxv = (c & 4) ? wx : omx;
        float wyv = (c & 2) ? wy : omy;
        float wzv = (c & 1) ? wz : omz;
        // forward: wc = (x*y)*z, each op rounded; f += fv*wc seq c=0..7
        float wgt = wxv * wyv;
        wgt = wgt * wzv;
        float t0 = fv.x * wgt;
        float t1 = fv.y * wgt;
        f0 = f0 + t0;
        f1 = f1 + t1;
        // gradient partials (sign flip by corner bit is exact)
        float pyz = wyv * wzv;
        float pxz = wxv * wzv;
        float pxy = wxv * wyv;
        float spx = (c & 4) ? pyz : -pyz;
        float spy = (c & 2) ? pxz : -pxz;
        float spz = (c & 1) ? pxy : -pxy;
        lxa = lxa + fv.x * spx;  lxb = lxb + fv.y * spx;
        lya = lya + fv.x * spy;  lyb = lyb + fv.y * spy;
        lza = lza + fv.x * spz;  lzb = lzb + fv.y * spz;
    }

    size_t LN = (size_t)NLV * N;
    size_t idx = (size_t)lvl * N + n;
    v2f* f2 = (v2f*)ws;                  // 2*LN floats
    v4f* p4 = (v4f*)(ws + 2*LN);         // 4*LN floats
    v2f* p2 = (v2f*)(ws + 6*LN);         // 2*LN floats
    v2f ff = {f0, f1};
    v4f pa = {lxa, lxb, lya, lyb};
    v2f pz = {lza, lzb};
    __builtin_nontemporal_store(ff, f2 + idx);
    __builtin_nontemporal_store(pa, p4 + idx);
    __builtin_nontemporal_store(pz, p2 + idx);
}

// =====================================================================
// PASS B: one thread per point. Plain cached ws loads (ws is L3-resident
// after pass A). COALESCED OUTPUT: the old per-thread op[] stores had
// lanes strided 156 B apart -> 64 L2 requests per store instruction,
// 10.2 M store-requests total (~50 us of L2 request budget). Now each
// half-tile of 128 points stages its 128x39 floats in LDS (per-thread
// writes at lane stride 39 dwords — odd, so conflict-free) and the whole
// block stores 1248 contiguous float4s, perfectly coalesced.
// =====================================================================
__global__ __launch_bounds__(256) void mlp_bwd(
    const float* __restrict__ g_pos,
    const float* __restrict__ g_rx,
    const float* __restrict__ g_W1,
    const float* __restrict__ g_W2,
    const float* __restrict__ g_aabb,
    const int*   __restrict__ g_deg,
    const float* __restrict__ ws,
    float* __restrict__ g_out,
    int N, ResT rt)
{
    __shared__ __align__(16) float so[128 * 39];   // 19,968 B

    int tid = threadIdx.x;
    int n = blockIdx.x * 256 + tid;
    bool alive = (n < N);
    int nc = alive ? n : (N - 1);                  // safe index for loads

    float posx = g_pos[3*nc+0], posy = g_pos[3*nc+1], posz = g_pos[3*nc+2];
    float s0, s1, s2, pnx, pny, pnz; bool sel;
    aabb_norm(g_aabb, posx, posy, posz, s0, s1, s2, pnx, pny, pnz, sel);
    (void)pnx; (void)pny; (void)pnz;

    size_t LN = (size_t)NLV * N;
    const v2f* f2 = (const v2f*)ws;
    const v4f* p4 = (const v4f*)(ws + 2*LN);
    const v2f* p2 = (const v2f*)(ws + 6*LN);

    // ---- z1 = feats@W1, exact level order, sgemm FMA chain ascending k ----
    float z1[32];
#pragma unroll
    for (int i = 0; i < 32; ++i) z1[i] = 0.f;
    for (int l = 0; l < NLV; ++l) {
        v2f fv = f2[(size_t)l * N + nc];
        float f0 = fv.x;
        float f1 = fv.y;
        const float* w1a = g_W1 + (2*l) * 32;
        const float* w1b = g_W1 + (2*l+1) * 32;
#pragma unroll
        for (int i = 0; i < 32; ++i) {
            float acc = fmaf(f0, w1a[i], z1[i]);   // k=2l then k=2l+1
            z1[i] = fmaf(f1, w1b[i], acc);
        }
    }

    // ---- relu + second layer (sgemm FMA chain, ascending j) ----
    unsigned mask = 0u;
    float sh[32];
#pragma unroll
    for (int o = 0; o < 32; ++o) sh[o] = 0.f;
#pragma unroll
    for (int i = 0; i < 32; ++i) {
        bool on = (z1[i] > 0.f);
        if (on) mask |= (1u << i);
        float h = on ? z1[i] : 0.f;
        const float* w2r = g_W2 + i * 32;
#pragma unroll
        for (int o = 0; o < 32; ++o) sh[o] = fmaf(h, w2r[o], sh[o]);
    }

    const float C0c = 0.28209479177387814f;
    float d0 = C0c * sh[0], d1 = C0c * sh[1];

    // ---- view dirs + SH basis + scat ----
    float rx0 = g_rx[0], rx1 = g_rx[1], rx2 = g_rx[2];
    float dxw = rx0 - posx, dyw = rx1 - posy, dzw = rx2 - posz;
    float dnorm = sqrtf(dxw*dxw + dyw*dyw + dzw*dzw);
    float dinv = 1.f / fmaxf(dnorm, 1e-20f);
    float X = dxw * dinv, Yd = dyw * dinv, Z = dzw * dinv;
    float xx = X*X, yy = Yd*Yd, zz = Z*Z;
    float xy = X*Yd, yz = Yd*Z, xz = X*Z;
    float Yb[16];
    Yb[0]  = 0.28209479177387814f;
    Yb[1]  = -0.4886025119029199f * Yd;
    Yb[2]  =  0.4886025119029199f * Z;
    Yb[3]  = -0.4886025119029199f * X;
    Yb[4]  =  1.0925484305920792f * xy;
    Yb[5]  = -1.0925484305920792f * yz;
    Yb[6]  =  0.31539156525252005f * (2.f*zz - xx - yy);
    Yb[7]  = -1.0925484305920792f * xz;
    Yb[8]  =  0.5462742152960396f * (xx - yy);
    Yb[9]  = -0.5900435899266435f * Yd * (3.f*xx - yy);
    Yb[10] =  2.890611442640554f  * xy * Z;
    Yb[11] = -0.4570457994644658f * Yd * (4.f*zz - xx - yy);
    Yb[12] =  0.3731763325901154f * Z * (2.f*zz - 3.f*xx - 3.f*yy);
    Yb[13] = -0.4570457994644658f * X * (4.f*zz - xx - yy);
    Yb[14] =  1.445305721320277f  * Z * (xx - yy);
    Yb[15] = -0.5900435899266435f * X * (xx - 3.f*yy);

    int deg = g_deg[0];
    int nact = (deg + 1) * (deg + 1);
    float sc0 = 0.f, sc1 = 0.f;
#pragma unroll
    for (int c = 0; c < 16; ++c) {
        float yc = (c < nact) ? Yb[c] : 0.f;
        sc0 = fmaf(yc, sh[2*c+0], sc0);
        sc1 = fmaf(yc, sh[2*c+1], sc1);
    }

    // ---- backward head: q = C0*d/|d| ----
    float ss = d0*d0 + d1*d1;
    float q0 = 0.f, q1 = 0.f;
    if (ss > 0.f) {
        float sr = sqrtf(ss);
        q0 = C0c * d0 / sr;
        q1 = C0c * d1 / sr;
    }
    float dzv[32];
#pragma unroll
    for (int i = 0; i < 32; ++i) {
        float dh = fmaf(q0, g_W2[i*32+0], q1 * g_W2[i*32+1]);
        dzv[i] = ((mask >> i) & 1u) ? dh : 0.f;
    }

    // ---- gradient: per level, da/db from W1 (L1-hit) x partials from ws ----
    float gx = 0.f, gy = 0.f, gz = 0.f;
    const float4* w1v = (const float4*)g_W1;   // row r = w1v[r*8 .. r*8+7]
    for (int l = 0; l < NLV; ++l) {
        // issue the two ws loads first; 32 fmafs below hide their latency
        v4f c4 = p4[(size_t)l * N + nc];
        v2f c2 = p2[(size_t)l * N + nc];
        const float4* wa = w1v + (size_t)(2*l) * 8;
        const float4* wb = wa + 8;
        float da = 0.f, db = 0.f;
#pragma unroll
        for (int k = 0; k < 8; ++k) {
            float4 va = wa[k], vb = wb[k];
            da = fmaf(va.x, dzv[4*k+0], da);
            da = fmaf(va.y, dzv[4*k+1], da);
            da = fmaf(va.z, dzv[4*k+2], da);
            da = fmaf(va.w, dzv[4*k+3], da);
            db = fmaf(vb.x, dzv[4*k+0], db);
            db = fmaf(vb.y, dzv[4*k+1], db);
            db = fmaf(vb.z, dzv[4*k+2], db);
            db = fmaf(vb.w, dzv[4*k+3], db);
        }
        float res = rt.r[l];
        gx = fmaf(res, fmaf(da, c4.x, db * c4.y), gx);
        gy = fmaf(res, fmaf(da, c4.z, db * c4.w), gy);
        gz = fmaf(res, fmaf(da, c2.x, db * c2.y), gz);
    }

    // ---- world-space normal ----
    float gwx = gx / s0, gwy = gy / s1, gwz = gz / s2;
    float gn = sqrtf(gwx*gwx + gwy*gwy + gwz*gwz);
    float ginv = -1.f / fmaxf(gn, 1e-20f);
    float nr0 = gwx * ginv, nr1 = gwy * ginv, nr2 = gwz * ginv;

    // ---- coalesced output via LDS staging (two 128-point half-tiles) ----
    for (int hh = 0; hh < 2; ++hh) {
        __syncthreads();
        if (((tid >> 7) == hh) && alive) {
            float* row = so + (size_t)(tid & 127) * 39;   // lane stride 39 dw: odd, conflict-free
            row[0] = sel ? d0  : 0.f;
            row[1] = sel ? d1  : 0.f;
            row[2] = sel ? sc0 : 0.f;
            row[3] = sel ? sc1 : 0.f;
            row[4] = sel ? nr0 : 0.f;
            row[5] = sel ? nr1 : 0.f;
            row[6] = sel ? nr2 : 0.f;
#pragma unroll
            for (int c = 0; c < 32; ++c) row[7 + c] = sel ? sh[c] : 0.f;
        }
        __syncthreads();
        int base_n = blockIdx.x * 256 + hh * 128;
        int cnt = N - base_n; if (cnt > 128) cnt = 128;
        if (cnt > 0) {
            int nf = cnt * 39;
            int nv = nf >> 2;
            float4* dst = (float4*)(g_out + (size_t)base_n * 39);
            const float4* src = (const float4*)so;
            for (int i = tid; i < nv; i += 256) dst[i] = src[i];
            int tail = nf & 3;
            if (tid < tail)
                ((float*)dst)[(nv << 2) + tid] = ((const float*)src)[(nv << 2) + tid];
        }
    }
}

// =====================================================================
// FALLBACK (round-7 fused kernel) if ws_size is too small.
// =====================================================================
__global__ __launch_bounds__(256, 2) void ngp_fused(
    const float* __restrict__ g_pos,
    const float* __restrict__ g_rx,
    const float* __restrict__ g_tab,
    const float* __restrict__ g_W1,
    const float* __restrict__ g_W2,
    const float* __restrict__ g_aabb,
    const int*   __restrict__ g_deg,
    float* __restrict__ g_out,
    int N, ResT rt)
{
    __shared__ float sm[48][256];

    int tid = blockIdx.x * 256 + threadIdx.x;
    int lt  = threadIdx.x;
    int n = tid >> 1;
    int p = tid & 1;
    if (n >= N) return;

    float posx = g_pos[3*n+0], posy = g_pos[3*n+1], posz = g_pos[3*n+2];
    float s0, s1, s2, pnx, pny, pnz; bool sel;
    aabb_norm(g_aabb, posx, posy, posz, s0, s1, s2, pnx, pny, pnz, sel);

    const float2* tab = (const float2*)g_tab;
    float f0o[8], f1o[8];
#pragma unroll
    for (int j = 0; j < 8; ++j) {
        float res = p ? rt.r[8+j] : rt.r[j];
        const float2* tl = tab + (size_t)(p * 8 + j) * TSZ;
        float fx = pnx * res, fy = pny * res, fz = pnz * res;
        float x0 = floorf(fx), y0 = floorf(fy), z0 = floorf(fz);
        float wx = fx - x0, wy = fy - y0, wz = fz - z0;
        float omx = 1.f - wx, omy = 1.f - wy, omz = 1.f - wz;
        unsigned ux = (unsigned)x0, uy = (unsigned)y0, uz = (unsigned)z0;
        unsigned hx0 = ux,        hx1 = ux + 1u;
        unsigned hy0 = uy * PR1,  hy1 = (uy + 1u) * PR1;
        unsigned hz0 = uz * PR2,  hz1 = (uz + 1u) * PR2;
        float f0 = 0.f, f1 = 0.f;
        float lxa = 0.f, lxb = 0.f, lya = 0.f, lyb = 0.f, lza = 0.f, lzb = 0.f;
#pragma unroll
        for (int c = 0; c < 8; ++c) {
            unsigned hh = ((c & 4) ? hx1 : hx0) ^ ((c & 2) ? hy1 : hy0) ^ ((c & 1) ? hz1 : hz0);
            float2 fv = tl[hh & TMASK];
            float wxv = (c & 4) ? wx : omx;
            float wyv = (c & 2) ? wy : omy;
            float wzv = (c & 1) ? wz : omz;
            float wgt = wxv * wyv;
            wgt = wgt * wzv;
            float t0 = fv.x * wgt;
            float t1 = fv.y * wgt;
            f0 = f0 + t0;
            f1 = f1 + t1;
            float pyz = wyv * wzv;
            float pxz = wxv * wzv;
            float pxy = wxv * wyv;
            float spx = (c & 4) ? pyz : -pyz;
            float spy = (c & 2) ? pxz : -pxz;
            float spz = (c & 1) ? pxy : -pxy;
            lxa = lxa + fv.x * spx;  lxb = lxb + fv.y * spx;
            lya = lya + fv.x * spy;  lyb = lyb + fv.y * spy;
            lza = lza + fv.x * spz;  lzb = lzb + fv.y * spz;
        }
        f0o[j] = f0; f1o[j] = f1;
        sm[j*6+0][lt] = lxa;  sm[j*6+1][lt] = lxb;
        sm[j*6+2][lt] = lya;  sm[j*6+3][lt] = lyb;
        sm[j*6+4][lt] = lza;  sm[j*6+5][lt] = lzb;
    }

    float z1[32];
#pragma unroll
    for (int i = 0; i < 32; ++i) z1[i] = 0.f;
    float hi0[8], hi1[8];
#pragma unroll
    for (int j = 0; j < 8; ++j) {
        float t0 = __shfl_xor(f0o[j], 1, 64);
        float t1 = __shfl_xor(f1o[j], 1, 64);
        float lo0 = p ? t0 : f0o[j];
        float lo1 = p ? t1 : f1o[j];
        hi0[j] = p ? f0o[j] : t0;
        hi1[j] = p ? f1o[j] : t1;
        const float* w1a = g_W1 + (2*j) * 32;
        const float* w1b = g_W1 + (2*j+1) * 32;
#pragma unroll
        for (int i = 0; i < 32; ++i) {
            float acc = fmaf(lo0, w1a[i], z1[i]);
            z1[i] = fmaf(lo1, w1b[i], acc);
        }
    }
#pragma unroll
    for (int j = 0; j < 8; ++j) {
        const float* w1a = g_W1 + (2*(8+j)) * 32;
        const float* w1b = g_W1 + (2*(8+j)+1) * 32;
#pragma unroll
        for (int i = 0; i < 32; ++i) {
            float acc = fmaf(hi0[j], w1a[i], z1[i]);
            z1[i] = fmaf(hi1[j], w1b[i], acc);
        }
    }

    unsigned mask = 0u;
    float sh[32];
#pragma unroll
    for (int o = 0; o < 32; ++o) sh[o] = 0.f;
#pragma unroll
    for (int i = 0; i < 32; ++i) {
        bool on = (z1[i] > 0.f);
        if (on) mask |= (1u << i);
        float h = on ? z1[i] : 0.f;
        const float* w2r = g_W2 + i * 32;
#pragma unroll
        for (int o = 0; o < 32; ++o) sh[o] = fmaf(h, w2r[o], sh[o]);
    }

    const float C0c = 0.28209479177387814f;
    float d0 = C0c * sh[0], d1 = C0c * sh[1];

    float rx0 = g_rx[0], rx1 = g_rx[1], rx2 = g_rx[2];
    float dxw = rx0 - posx, dyw = rx1 - posy, dzw = rx2 - posz;
    float dnorm = sqrtf(dxw*dxw + dyw*dyw + dzw*dzw);
    float dinv = 1.f / fmaxf(dnorm, 1e-20f);
    float X = dxw * dinv, Yd = dyw * dinv, Z = dzw * dinv;
    float xx = X*X, yy = Yd*Yd, zz = Z*Z;
    float xy = X*Yd, yz = Yd*Z, xz = X*Z;
    float Yb[16];
    Yb[0]  = 0.28209479177387814f;
    Yb[1]  = -0.4886025119029199f * Yd;
    Yb[2]  =  0.4886025119029199f * Z;
    Yb[3]  = -0.4886025119029199f * X;
    Yb[4]  =  1.0925484305920792f * xy;
    Yb[5]  = -1.0925484305920792f * yz;
    Yb[6]  =  0.31539156525252005f * (2.f*zz - xx - yy);
    Yb[7]  = -1.0925484305920792f * xz;
    Yb[8]  =  0.5462742152960396f * (xx - yy);
    Yb[9]  = -0.5900435899266435f * Yd * (3.f*xx - yy);
    Yb[10] =  2.890611442640554f  * xy * Z;
    Yb[11] = -0.4570457994644658f * Yd * (4.f*zz - xx - yy);
    Yb[12] =  0.3731763325901154f * Z * (2.f*zz - 3.f*xx - 3.f*yy);
    Yb[13] = -0.4570457994644658f * X * (4.f*zz - xx - yy);
    Yb[14] =  1.445305721320277f  * Z * (xx - yy);
    Yb[15] = -0.5900435899266435f * X * (xx - 3.f*yy);

    int deg = g_deg[0];
    int nact = (deg + 1) * (deg + 1);
    float sc0 = 0.f, sc1 = 0.f;
#pragma unroll
    for (int c = 0; c < 16; ++c) {
        float yc = (c < nact) ? Yb[c] : 0.f;
        sc0 = fmaf(yc, sh[2*c+0], sc0);
        sc1 = fmaf(yc, sh[2*c+1], sc1);
    }

    float* op = g_out + (size_t)n * 39;
    if (p == 0) {
        op[0] = sel ? d0  : 0.f;
        op[1] = sel ? d1  : 0.f;
        op[2] = sel ? sc0 : 0.f;
        op[3] = sel ? sc1 : 0.f;
#pragma unroll
        for (int c = 0; c < 13; ++c) op[7 + c] = sel ? sh[c] : 0.f;
    } else {
#pragma unroll
        for (int c = 13; c < 32; ++c) op[7 + c] = sel ? sh[c] : 0.f;
    }

    float ss = d0*d0 + d1*d1;
    float q0 = 0.f, q1 = 0.f;
    if (ss > 0.f) {
        float sr = sqrtf(ss);
        q0 = C0c * d0 / sr;
        q1 = C0c * d1 / sr;
    }
    float dzv[32];
#pragma unroll
    for (int i = 0; i < 32; ++i) {
        float dh = fmaf(q0, g_W2[i*32+0], q1 * g_W2[i*32+1]);
        dzv[i] = ((mask >> i) & 1u) ? dh : 0.f;
    }

    float gx = 0.f, gy = 0.f, gz = 0.f;
    const float4* w1v = (const float4*)g_W1;
    int rbase = p * 16;
#pragma unroll
    for (int j = 0; j < 8; ++j) {
        const float4* wa = w1v + (size_t)(rbase + 2*j) * 8;
        const float4* wb = wa + 8;
        float da = 0.f, db = 0.f;
#pragma unroll
        for (int k = 0; k < 8; ++k) {
            float4 va = wa[k], vb = wb[k];
            da = fmaf(va.x, dzv[4*k+0], da);
            da = fmaf(va.y, dzv[4*k+1], da);
            da = fmaf(va.z, dzv[4*k+2], da);
            da = fmaf(va.w, dzv[4*k+3], da);
            db = fmaf(vb.x, dzv[4*k+0], db);
            db = fmaf(vb.y, dzv[4*k+1], db);
            db = fmaf(vb.z, dzv[4*k+2], db);
            db = fmaf(vb.w, dzv[4*k+3], db);
        }
        float xa = sm[j*6+0][lt], xb = sm[j*6+1][lt];
        float ya = sm[j*6+2][lt], yb = sm[j*6+3][lt];
        float za = sm[j*6+4][lt], zb = sm[j*6+5][lt];
        float res = p ? rt.r[8+j] : rt.r[j];
        gx = fmaf(res, fmaf(da, xa, db * xb), gx);
        gy = fmaf(res, fmaf(da, ya, db * yb), gy);
        gz = fmaf(res, fmaf(da, za, db * zb), gz);
    }
    float tx = __shfl_xor(gx, 1, 64);
    float ty = __shfl_xor(gy, 1, 64);
    float tz = __shfl_xor(gz, 1, 64);
    gx = gx + tx; gy = gy + ty; gz = gz + tz;

    float gwx = gx / s0, gwy = gy / s1, gwz = gz / s2;
    float gn = sqrtf(gwx*gwx + gwy*gwy + gwz*gwz);
    float ginv = -1.f / fmaxf(gn, 1e-20f);
    if (p == 0) {
        op[4] = sel ? gwx * ginv : 0.f;
        op[5] = sel ? gwy * ginv : 0.f;
        op[6] = sel ? gwz * ginv : 0.f;
    }
}

extern "C" void kernel_launch(void* const* d_in, const int* in_sizes, int n_in,
                              void* d_out, int out_size, void* d_ws, size_t ws_size,
                              hipStream_t stream)
{
    const float* g_pos  = (const float*)d_in[0];
    const float* g_rx   = (const float*)d_in[1];
    const float* g_tab  = (const float*)d_in[2];
    const float* g_W1   = (const float*)d_in[3];
    const float* g_W2   = (const float*)d_in[4];
    const float* g_aabb = (const float*)d_in[5];
    const int*   g_deg  = (const int*)d_in[6];
    float* g_out = (float*)d_out;

    int N = in_sizes[0] / 3;

    // RES exactly as the reference: python float64 exp/log/pow, cast to fp32.
    ResT rt;
    double scale = exp((log(4096.0) - log(16.0)) / 15.0);
    for (int l = 0; l < NLV; ++l) rt.r[l] = (float)(16.0 * pow(scale, (double)l));

    size_t need = (size_t)NLV * N * 8 * sizeof(float);   // 134 MB at N=262144
    if (ws_size >= need) {
        float* ws = (float*)d_ws;
        int chunks = (N + 255) / 256;
        level_gather<<<NLV * chunks, 256, 0, stream>>>(g_pos, g_tab, g_aabb,
                                                       ws, N, chunks, rt);
        mlp_bwd<<<chunks, 256, 0, stream>>>(g_pos, g_rx, g_W1, g_W2, g_aabb,
                                            g_deg, ws, g_out, N, rt);
    } else {
        long long threads = 2LL * N;
        int blocks = (int)((threads + 255) / 256);
        ngp_fused<<<blocks, 256, 0, stream>>>(g_pos, g_rx, g_tab, g_W1, g_W2,
                                              g_aabb, g_deg, g_out, N, rt);
    }
}

// Round 4
// 327.379 us; speedup vs baseline: 1.2011x; 1.0246x over previous
//
#include <hip/hip_runtime.h>
#include <cmath>

// Forbid FMA contraction: the reference check is a float32 numpy replay with
// individually-rounded ops. We opt into FMA explicitly (fmaf) only where
// BLAS sgemm itself uses an FMA chain.
#pragma clang fp contract(off)

#define NLV 16
#define TSZ (1u << 19)
#define TMASK (TSZ - 1u)
#define PR1 2654435761u
#define PR2 805459861u

typedef float v2f __attribute__((ext_vector_type(2)));
typedef float v4f __attribute__((ext_vector_type(4)));

struct ResT { float r[NLV]; };

// ---------- shared helpers (bit-exact fp32, matches np reference) ----------
__device__ __forceinline__ void aabb_norm(
    const float* __restrict__ g_aabb, float posx, float posy, float posz,
    float& s0, float& s1, float& s2,
    float& pnx, float& pny, float& pnz, bool& sel)
{
    float a0 = g_aabb[0], a1 = g_aabb[1], a2 = g_aabb[2];
    s0 = fmaxf(g_aabb[3] - a0, 1e-6f);
    s1 = fmaxf(g_aabb[4] - a1, 1e-6f);
    s2 = fmaxf(g_aabb[5] - a2, 1e-6f);
    float nx = (posx - a0) / s0;
    float ny = (posy - a1) / s1;
    float nz = (posz - a2) / s2;
    sel = (nx >= 0.f) && (nx <= 1.f) && (ny >= 0.f) && (ny <= 1.f)
       && (nz >= 0.f) && (nz <= 1.f);
    pnx = fminf(fmaxf(nx, 0.f), 1.f);
    pny = fminf(fmaxf(ny, 0.f), 1.f);
    pnz = fminf(fmaxf(nz, 0.f), 1.f);
}

// =====================================================================
// PASS A: one (point, level) per thread. ROUND-1 MAPPING (measured best,
// ~168 us, FETCH 95 MB): two time phases; phase 0 runs levels 0..7 with
// level l pinned to XCD l (b%8 round-robin), phase 1 runs levels 8..15.
// Each XCD holds exactly ONE 4 MB slice at a time -> slice L2-resident.
// Measured floor: 16 levels x 2.1M random 8B gathers / 8 XCDs at ~10.2
// req/cyc/XCD = ~170 us; request count per XCD is mapping-invariant and
// even level 0's cell set (39 KB) exceeds L1, so every level is
// L2-random. This pass is at its structural floor.
// ws stores NON-TEMPORAL: keeps the 131 MB stream from evicting the
// pinned slice out of L2. (Whether nt also bypasses L3 is moot now:
// pass B is made latency-tolerant by deep prefetch.)
// ws layout packed for pass B:
//   f2[l*N+n]  = (f0,f1)           (v2f plane)
//   p4[l*N+n]  = (xa,xb,ya,yb)     (v4f plane)
//   p2[l*N+n]  = (za,zb)           (v2f plane)
// =====================================================================
__global__ __launch_bounds__(256) void level_gather(
    const float* __restrict__ g_pos,
    const float* __restrict__ g_tab,
    const float* __restrict__ g_aabb,
    float* __restrict__ ws,
    int N, int chunks, ResT rt)
{
    int b = blockIdx.x;
    int half = (b >= 8 * chunks) ? 1 : 0;
    int bb = b - half * (8 * chunks);
    int lvl = (bb & 7) + (half << 3);
    int n = (bb >> 3) * 256 + threadIdx.x;
    if (n >= N) return;

    float posx = g_pos[3*n+0], posy = g_pos[3*n+1], posz = g_pos[3*n+2];
    float s0, s1, s2, pnx, pny, pnz; bool sel;
    aabb_norm(g_aabb, posx, posy, posz, s0, s1, s2, pnx, pny, pnz, sel);

    float res = rt.r[lvl];                       // wave-uniform scalar
    const float2* tl = (const float2*)g_tab + (size_t)lvl * TSZ;

    float fx = pnx * res, fy = pny * res, fz = pnz * res;
    float x0 = floorf(fx), y0 = floorf(fy), z0 = floorf(fz);
    float wx = fx - x0, wy = fy - y0, wz = fz - z0;
    float omx = 1.f - wx, omy = 1.f - wy, omz = 1.f - wz;
    unsigned ux = (unsigned)x0, uy = (unsigned)y0, uz = (unsigned)z0;
    unsigned hx0 = ux,        hx1 = ux + 1u;
    unsigned hy0 = uy * PR1,  hy1 = (uy + 1u) * PR1;
    unsigned hz0 = uz * PR2,  hz1 = (uz + 1u) * PR2;
    float f0 = 0.f, f1 = 0.f;
    float lxa = 0.f, lxb = 0.f, lya = 0.f, lyb = 0.f, lza = 0.f, lzb = 0.f;
#pragma unroll
    for (int c = 0; c < 8; ++c) {
        unsigned hh = ((c & 4) ? hx1 : hx0) ^ ((c & 2) ? hy1 : hy0) ^ ((c & 1) ? hz1 : hz0);
        float2 fv = tl[hh & TMASK];
        float wxv = (c & 4) ? wx : omx;
        float wyv = (c & 2) ? wy : omy;
        float wzv = (c & 1) ? wz : omz;
        // forward: wc = (x*y)*z, each op rounded; f += fv*wc seq c=0..7
        float wgt = wxv * wyv;
        wgt = wgt * wzv;
        float t0 = fv.x * wgt;
        float t1 = fv.y * wgt;
        f0 = f0 + t0;
        f1 = f1 + t1;
        // gradient partials (sign flip by corner bit is exact)
        float pyz = wyv * wzv;
        float pxz = wxv * wzv;
        float pxy = wxv * wyv;
        float spx = (c & 4) ? pyz : -pyz;
        float spy = (c & 2) ? pxz : -pxz;
        float spz = (c & 1) ? pxy : -pxy;
        lxa = lxa + fv.x * spx;  lxb = lxb + fv.y * spx;
        lya = lya + fv.x * spy;  lyb = lyb + fv.y * spy;
        lza = lza + fv.x * spz;  lzb = lzb + fv.y * spz;
    }

    size_t LN = (size_t)NLV * N;
    size_t idx = (size_t)lvl * N + n;
    v2f* f2 = (v2f*)ws;                  // 2*LN floats
    v4f* p4 = (v4f*)(ws + 2*LN);         // 4*LN floats
    v2f* p2 = (v2f*)(ws + 6*LN);         // 2*LN floats
    v2f ff = {f0, f1};
    v4f pa = {lxa, lxb, lya, lyb};
    v2f pz = {lza, lzb};
    __builtin_nontemporal_store(ff, f2 + idx);
    __builtin_nontemporal_store(pa, p4 + idx);
    __builtin_nontemporal_store(pz, p2 + idx);
}

// =====================================================================
// PASS B: one thread per point. LATENCY-TOLERANT: the old rolled loops
// exposed ONE outstanding ws load per wave (result consumed in-iteration)
// -> ~16 req/CU vs ~700cyc latency = ~160 us (Little's law, matches r3).
// Now: 4-deep rolling prefetch on f2 in the z1 loop (statically indexed,
// full unroll), and 4-deep rolling prefetch on p4/p2 in the grad loop
// with the first 4 issued BEFORE the forward so they ride under ~2000
// fmafs. FP order unchanged. Output stays LDS-staged + coalesced.
// =====================================================================
__global__ __launch_bounds__(256) void mlp_bwd(
    const float* __restrict__ g_pos,
    const float* __restrict__ g_rx,
    const float* __restrict__ g_W1,
    const float* __restrict__ g_W2,
    const float* __restrict__ g_aabb,
    const int*   __restrict__ g_deg,
    const float* __restrict__ ws,
    float* __restrict__ g_out,
    int N, ResT rt)
{
    __shared__ __align__(16) float so[128 * 39];   // 19,968 B

    int tid = threadIdx.x;
    int n = blockIdx.x * 256 + tid;
    bool alive = (n < N);
    int nc = alive ? n : (N - 1);                  // safe index for loads

    size_t LN = (size_t)NLV * N;
    const v2f* f2 = (const v2f*)ws;
    const v4f* p4 = (const v4f*)(ws + 2*LN);
    const v2f* p2 = (const v2f*)(ws + 6*LN);

    // ---- issue early loads: first 4 f2 and first 4 p4/p2 ----
    v2f fv[4];
#pragma unroll
    for (int j = 0; j < 4; ++j) fv[j] = f2[(size_t)j * N + nc];
    v4f pc4[4];
    v2f pc2[4];
#pragma unroll
    for (int j = 0; j < 4; ++j) {
        pc4[j] = p4[(size_t)j * N + nc];
        pc2[j] = p2[(size_t)j * N + nc];
    }

    float posx = g_pos[3*nc+0], posy = g_pos[3*nc+1], posz = g_pos[3*nc+2];
    float s0, s1, s2, pnx, pny, pnz; bool sel;
    aabb_norm(g_aabb, posx, posy, posz, s0, s1, s2, pnx, pny, pnz, sel);
    (void)pnx; (void)pny; (void)pnz;

    // ---- z1 = feats@W1, exact level order, sgemm FMA chain ascending k ----
    float z1[32];
#pragma unroll
    for (int i = 0; i < 32; ++i) z1[i] = 0.f;
#pragma unroll
    for (int l = 0; l < NLV; ++l) {
        v2f fvl = fv[l & 3];
        if (l + 4 < NLV) fv[l & 3] = f2[(size_t)(l + 4) * N + nc];  // 4 ahead
        float f0 = fvl.x;
        float f1 = fvl.y;
        const float* w1a = g_W1 + (2*l) * 32;
        const float* w1b = g_W1 + (2*l+1) * 32;
#pragma unroll
        for (int i = 0; i < 32; ++i) {
            float acc = fmaf(f0, w1a[i], z1[i]);   // k=2l then k=2l+1
            z1[i] = fmaf(f1, w1b[i], acc);
        }
    }

    // ---- relu + second layer (sgemm FMA chain, ascending j) ----
    unsigned mask = 0u;
    float sh[32];
#pragma unroll
    for (int o = 0; o < 32; ++o) sh[o] = 0.f;
#pragma unroll
    for (int i = 0; i < 32; ++i) {
        bool on = (z1[i] > 0.f);
        if (on) mask |= (1u << i);
        float h = on ? z1[i] : 0.f;
        const float* w2r = g_W2 + i * 32;
#pragma unroll
        for (int o = 0; o < 32; ++o) sh[o] = fmaf(h, w2r[o], sh[o]);
    }

    const float C0c = 0.28209479177387814f;
    float d0 = C0c * sh[0], d1 = C0c * sh[1];

    // ---- view dirs + SH basis + scat ----
    float rx0 = g_rx[0], rx1 = g_rx[1], rx2 = g_rx[2];
    float dxw = rx0 - posx, dyw = rx1 - posy, dzw = rx2 - posz;
    float dnorm = sqrtf(dxw*dxw + dyw*dyw + dzw*dzw);
    float dinv = 1.f / fmaxf(dnorm, 1e-20f);
    float X = dxw * dinv, Yd = dyw * dinv, Z = dzw * dinv;
    float xx = X*X, yy = Yd*Yd, zz = Z*Z;
    float xy = X*Yd, yz = Yd*Z, xz = X*Z;
    float Yb[16];
    Yb[0]  = 0.28209479177387814f;
    Yb[1]  = -0.4886025119029199f * Yd;
    Yb[2]  =  0.4886025119029199f * Z;
    Yb[3]  = -0.4886025119029199f * X;
    Yb[4]  =  1.0925484305920792f * xy;
    Yb[5]  = -1.0925484305920792f * yz;
    Yb[6]  =  0.31539156525252005f * (2.f*zz - xx - yy);
    Yb[7]  = -1.0925484305920792f * xz;
    Yb[8]  =  0.5462742152960396f * (xx - yy);
    Yb[9]  = -0.5900435899266435f * Yd * (3.f*xx - yy);
    Yb[10] =  2.890611442640554f  * xy * Z;
    Yb[11] = -0.4570457994644658f * Yd * (4.f*zz - xx - yy);
    Yb[12] =  0.3731763325901154f * Z * (2.f*zz - 3.f*xx - 3.f*yy);
    Yb[13] = -0.4570457994644658f * X * (4.f*zz - xx - yy);
    Yb[14] =  1.445305721320277f  * Z * (xx - yy);
    Yb[15] = -0.5900435899266435f * X * (xx - 3.f*yy);

    int deg = g_deg[0];
    int nact = (deg + 1) * (deg + 1);
    float sc0 = 0.f, sc1 = 0.f;
#pragma unroll
    for (int c = 0; c < 16; ++c) {
        float yc = (c < nact) ? Yb[c] : 0.f;
        sc0 = fmaf(yc, sh[2*c+0], sc0);
        sc1 = fmaf(yc, sh[2*c+1], sc1);
    }

    // ---- backward head: q = C0*d/|d| ----
    float ss = d0*d0 + d1*d1;
    float q0 = 0.f, q1 = 0.f;
    if (ss > 0.f) {
        float sr = sqrtf(ss);
        q0 = C0c * d0 / sr;
        q1 = C0c * d1 / sr;
    }
    float dzv[32];
#pragma unroll
    for (int i = 0; i < 32; ++i) {
        float dh = fmaf(q0, g_W2[i*32+0], q1 * g_W2[i*32+1]);
        dzv[i] = ((mask >> i) & 1u) ? dh : 0.f;
    }

    // ---- gradient: per level, da/db from W1 (L1-hit) x partials from ws ----
    // pc4/pc2[0..3] were issued before the forward; keep 4 levels ahead.
    float gx = 0.f, gy = 0.f, gz = 0.f;
    const float4* w1v = (const float4*)g_W1;   // row r = w1v[r*8 .. r*8+7]
#pragma unroll
    for (int l = 0; l < NLV; ++l) {
        v4f c4 = pc4[l & 3];
        v2f c2 = pc2[l & 3];
        if (l + 4 < NLV) {
            pc4[l & 3] = p4[(size_t)(l + 4) * N + nc];   // 4 ahead
            pc2[l & 3] = p2[(size_t)(l + 4) * N + nc];
        }
        const float4* wa = w1v + (size_t)(2*l) * 8;
        const float4* wb = wa + 8;
        float da = 0.f, db = 0.f;
#pragma unroll
        for (int k = 0; k < 8; ++k) {
            float4 va = wa[k], vb = wb[k];
            da = fmaf(va.x, dzv[4*k+0], da);
            da = fmaf(va.y, dzv[4*k+1], da);
            da = fmaf(va.z, dzv[4*k+2], da);
            da = fmaf(va.w, dzv[4*k+3], da);
            db = fmaf(vb.x, dzv[4*k+0], db);
            db = fmaf(vb.y, dzv[4*k+1], db);
            db = fmaf(vb.z, dzv[4*k+2], db);
            db = fmaf(vb.w, dzv[4*k+3], db);
        }
        float res = rt.r[l];
        gx = fmaf(res, fmaf(da, c4.x, db * c4.y), gx);
        gy = fmaf(res, fmaf(da, c4.z, db * c4.w), gy);
        gz = fmaf(res, fmaf(da, c2.x, db * c2.y), gz);
    }

    // ---- world-space normal ----
    float gwx = gx / s0, gwy = gy / s1, gwz = gz / s2;
    float gn = sqrtf(gwx*gwx + gwy*gwy + gwz*gwz);
    float ginv = -1.f / fmaxf(gn, 1e-20f);
    float nr0 = gwx * ginv, nr1 = gwy * ginv, nr2 = gwz * ginv;

    // ---- coalesced output via LDS staging (two 128-point half-tiles) ----
    for (int hh = 0; hh < 2; ++hh) {
        __syncthreads();
        if (((tid >> 7) == hh) && alive) {
            float* row = so + (size_t)(tid & 127) * 39;   // lane stride 39 dw: odd, conflict-free
            row[0] = sel ? d0  : 0.f;
            row[1] = sel ? d1  : 0.f;
            row[2] = sel ? sc0 : 0.f;
            row[3] = sel ? sc1 : 0.f;
            row[4] = sel ? nr0 : 0.f;
            row[5] = sel ? nr1 : 0.f;
            row[6] = sel ? nr2 : 0.f;
#pragma unroll
            for (int c = 0; c < 32; ++c) row[7 + c] = sel ? sh[c] : 0.f;
        }
        __syncthreads();
        int base_n = blockIdx.x * 256 + hh * 128;
        int cnt = N - base_n; if (cnt > 128) cnt = 128;
        if (cnt > 0) {
            int nf = cnt * 39;
            int nv = nf >> 2;
            float4* dst = (float4*)(g_out + (size_t)base_n * 39);
            const float4* src = (const float4*)so;
            for (int i = tid; i < nv; i += 256) dst[i] = src[i];
            int tail = nf & 3;
            if (tid < tail)
                ((float*)dst)[(nv << 2) + tid] = ((const float*)src)[(nv << 2) + tid];
        }
    }
}

// =====================================================================
// FALLBACK (round-7 fused kernel) if ws_size is too small.
// =====================================================================
__global__ __launch_bounds__(256, 2) void ngp_fused(
    const float* __restrict__ g_pos,
    const float* __restrict__ g_rx,
    const float* __restrict__ g_tab,
    const float* __restrict__ g_W1,
    const float* __restrict__ g_W2,
    const float* __restrict__ g_aabb,
    const int*   __restrict__ g_deg,
    float* __restrict__ g_out,
    int N, ResT rt)
{
    __shared__ float sm[48][256];

    int tid = blockIdx.x * 256 + threadIdx.x;
    int lt  = threadIdx.x;
    int n = tid >> 1;
    int p = tid & 1;
    if (n >= N) return;

    float posx = g_pos[3*n+0], posy = g_pos[3*n+1], posz = g_pos[3*n+2];
    float s0, s1, s2, pnx, pny, pnz; bool sel;
    aabb_norm(g_aabb, posx, posy, posz, s0, s1, s2, pnx, pny, pnz, sel);

    const float2* tab = (const float2*)g_tab;
    float f0o[8], f1o[8];
#pragma unroll
    for (int j = 0; j < 8; ++j) {
        float res = p ? rt.r[8+j] : rt.r[j];
        const float2* tl = tab + (size_t)(p * 8 + j) * TSZ;
        float fx = pnx * res, fy = pny * res, fz = pnz * res;
        float x0 = floorf(fx), y0 = floorf(fy), z0 = floorf(fz);
        float wx = fx - x0, wy = fy - y0, wz = fz - z0;
        float omx = 1.f - wx, omy = 1.f - wy, omz = 1.f - wz;
        unsigned ux = (unsigned)x0, uy = (unsigned)y0, uz = (unsigned)z0;
        unsigned hx0 = ux,        hx1 = ux + 1u;
        unsigned hy0 = uy * PR1,  hy1 = (uy + 1u) * PR1;
        unsigned hz0 = uz * PR2,  hz1 = (uz + 1u) * PR2;
        float f0 = 0.f, f1 = 0.f;
        float lxa = 0.f, lxb = 0.f, lya = 0.f, lyb = 0.f, lza = 0.f, lzb = 0.f;
#pragma unroll
        for (int c = 0; c < 8; ++c) {
            unsigned hh = ((c & 4) ? hx1 : hx0) ^ ((c & 2) ? hy1 : hy0) ^ ((c & 1) ? hz1 : hz0);
            float2 fv = tl[hh & TMASK];
            float wxv = (c & 4) ? wx : omx;
            float wyv = (c & 2) ? wy : omy;
            float wzv = (c & 1) ? wz : omz;
            float wgt = wxv * wyv;
            wgt = wgt * wzv;
            float t0 = fv.x * wgt;
            float t1 = fv.y * wgt;
            f0 = f0 + t0;
            f1 = f1 + t1;
            float pyz = wyv * wzv;
            float pxz = wxv * wzv;
            float pxy = wxv * wyv;
            float spx = (c & 4) ? pyz : -pyz;
            float spy = (c & 2) ? pxz : -pxz;
            float spz = (c & 1) ? pxy : -pxy;
            lxa = lxa + fv.x * spx;  lxb = lxb + fv.y * spx;
            lya = lya + fv.x * spy;  lyb = lyb + fv.y * spy;
            lza = lza + fv.x * spz;  lzb = lzb + fv.y * spz;
        }
        f0o[j] = f0; f1o[j] = f1;
        sm[j*6+0][lt] = lxa;  sm[j*6+1][lt] = lxb;
        sm[j*6+2][lt] = lya;  sm[j*6+3][lt] = lyb;
        sm[j*6+4][lt] = lza;  sm[j*6+5][lt] = lzb;
    }

    float z1[32];
#pragma unroll
    for (int i = 0; i < 32; ++i) z1[i] = 0.f;
    float hi0[8], hi1[8];
#pragma unroll
    for (int j = 0; j < 8; ++j) {
        float t0 = __shfl_xor(f0o[j], 1, 64);
        float t1 = __shfl_xor(f1o[j], 1, 64);
        float lo0 = p ? t0 : f0o[j];
        float lo1 = p ? t1 : f1o[j];
        hi0[j] = p ? f0o[j] : t0;
        hi1[j] = p ? f1o[j] : t1;
        const float* w1a = g_W1 + (2*j) * 32;
        const float* w1b = g_W1 + (2*j+1) * 32;
#pragma unroll
        for (int i = 0; i < 32; ++i) {
            float acc = fmaf(lo0, w1a[i], z1[i]);
            z1[i] = fmaf(lo1, w1b[i], acc);
        }
    }
#pragma unroll
    for (int j = 0; j < 8; ++j) {
        const float* w1a = g_W1 + (2*(8+j)) * 32;
        const float* w1b = g_W1 + (2*(8+j)+1) * 32;
#pragma unroll
        for (int i = 0; i < 32; ++i) {
            float acc = fmaf(hi0[j], w1a[i], z1[i]);
            z1[i] = fmaf(hi1[j], w1b[i], acc);
        }
    }

    unsigned mask = 0u;
    float sh[32];
#pragma unroll
    for (int o = 0; o < 32; ++o) sh[o] = 0.f;
#pragma unroll
    for (int i = 0; i < 32; ++i) {
        bool on = (z1[i] > 0.f);
        if (on) mask |= (1u << i);
        float h = on ? z1[i] : 0.f;
        const float* w2r = g_W2 + i * 32;
#pragma unroll
        for (int o = 0; o < 32; ++o) sh[o] = fmaf(h, w2r[o], sh[o]);
    }

    const float C0c = 0.28209479177387814f;
    float d0 = C0c * sh[0], d1 = C0c * sh[1];

    float rx0 = g_rx[0], rx1 = g_rx[1], rx2 = g_rx[2];
    float dxw = rx0 - posx, dyw = rx1 - posy, dzw = rx2 - posz;
    float dnorm = sqrtf(dxw*dxw + dyw*dyw + dzw*dzw);
    float dinv = 1.f / fmaxf(dnorm, 1e-20f);
    float X = dxw * dinv, Yd = dyw * dinv, Z = dzw * dinv;
    float xx = X*X, yy = Yd*Yd, zz = Z*Z;
    float xy = X*Yd, yz = Yd*Z, xz = X*Z;
    float Yb[16];
    Yb[0]  = 0.28209479177387814f;
    Yb[1]  = -0.4886025119029199f * Yd;
    Yb[2]  =  0.4886025119029199f * Z;
    Yb[3]  = -0.4886025119029199f * X;
    Yb[4]  =  1.0925484305920792f * xy;
    Yb[5]  = -1.0925484305920792f * yz;
    Yb[6]  =  0.31539156525252005f * (2.f*zz - xx - yy);
    Yb[7]  = -1.0925484305920792f * xz;
    Yb[8]  =  0.5462742152960396f * (xx - yy);
    Yb[9]  = -0.5900435899266435f * Yd * (3.f*xx - yy);
    Yb[10] =  2.890611442640554f  * xy * Z;
    Yb[11] = -0.4570457994644658f * Yd * (4.f*zz - xx - yy);
    Yb[12] =  0.3731763325901154f * Z * (2.f*zz - 3.f*xx - 3.f*yy);
    Yb[13] = -0.4570457994644658f * X * (4.f*zz - xx - yy);
    Yb[14] =  1.445305721320277f  * Z * (xx - yy);
    Yb[15] = -0.5900435899266435f * X * (xx - 3.f*yy);

    int deg = g_deg[0];
    int nact = (deg + 1) * (deg + 1);
    float sc0 = 0.f, sc1 = 0.f;
#pragma unroll
    for (int c = 0; c < 16; ++c) {
        float yc = (c < nact) ? Yb[c] : 0.f;
        sc0 = fmaf(yc, sh[2*c+0], sc0);
        sc1 = fmaf(yc, sh[2*c+1], sc1);
    }

    float* op = g_out + (size_t)n * 39;
    if (p == 0) {
        op[0] = sel ? d0  : 0.f;
        op[1] = sel ? d1  : 0.f;
        op[2] = sel ? sc0 : 0.f;
        op[3] = sel ? sc1 : 0.f;
#pragma unroll
        for (int c = 0; c < 13; ++c) op[7 + c] = sel ? sh[c] : 0.f;
    } else {
#pragma unroll
        for (int c = 13; c < 32; ++c) op[7 + c] = sel ? sh[c] : 0.f;
    }

    float ss = d0*d0 + d1*d1;
    float q0 = 0.f, q1 = 0.f;
    if (ss > 0.f) {
        float sr = sqrtf(ss);
        q0 = C0c * d0 / sr;
        q1 = C0c * d1 / sr;
    }
    float dzv[32];
#pragma unroll
    for (int i = 0; i < 32; ++i) {
        float dh = fmaf(q0, g_W2[i*32+0], q1 * g_W2[i*32+1]);
        dzv[i] = ((mask >> i) & 1u) ? dh : 0.f;
    }

    float gx = 0.f, gy = 0.f, gz = 0.f;
    const float4* w1v = (const float4*)g_W1;
    int rbase = p * 16;
#pragma unroll
    for (int j = 0; j < 8; ++j) {
        const float4* wa = w1v + (size_t)(rbase + 2*j) * 8;
        const float4* wb = wa + 8;
        float da = 0.f, db = 0.f;
#pragma unroll
        for (int k = 0; k < 8; ++k) {
            float4 va = wa[k], vb = wb[k];
            da = fmaf(va.x, dzv[4*k+0], da);
            da = fmaf(va.y, dzv[4*k+1], da);
            da = fmaf(va.z, dzv[4*k+2], da);
            da = fmaf(va.w, dzv[4*k+3], da);
            db = fmaf(vb.x, dzv[4*k+0], db);
            db = fmaf(vb.y, dzv[4*k+1], db);
            db = fmaf(vb.z, dzv[4*k+2], db);
            db = fmaf(vb.w, dzv[4*k+3], db);
        }
        float xa = sm[j*6+0][lt], xb = sm[j*6+1][lt];
        float ya = sm[j*6+2][lt], yb = sm[j*6+3][lt];
        float za = sm[j*6+4][lt], zb = sm[j*6+5][lt];
        float res = p ? rt.r[8+j] : rt.r[j];
        gx = fmaf(res, fmaf(da, xa, db * xb), gx);
        gy = fmaf(res, fmaf(da, ya, db * yb), gy);
        gz = fmaf(res, fmaf(da, za, db * zb), gz);
    }
    float tx = __shfl_xor(gx, 1, 64);
    float ty = __shfl_xor(gy, 1, 64);
    float tz = __shfl_xor(gz, 1, 64);
    gx = gx + tx; gy = gy + ty; gz = gz + tz;

    float gwx = gx / s0, gwy = gy / s1, gwz = gz / s2;
    float gn = sqrtf(gwx*gwx + gwy*gwy + gwz*gwz);
    float ginv = -1.f / fmaxf(gn, 1e-20f);
    if (p == 0) {
        op[4] = sel ? gwx * ginv : 0.f;
        op[5] = sel ? gwy * ginv : 0.f;
        op[6] = sel ? gwz * ginv : 0.f;
    }
}

extern "C" void kernel_launch(void* const* d_in, const int* in_sizes, int n_in,
                              void* d_out, int out_size, void* d_ws, size_t ws_size,
                              hipStream_t stream)
{
    const float* g_pos  = (const float*)d_in[0];
    const float* g_rx   = (const float*)d_in[1];
    const float* g_tab  = (const float*)d_in[2];
    const float* g_W1   = (const float*)d_in[3];
    const float* g_W2   = (const float*)d_in[4];
    const float* g_aabb = (const float*)d_in[5];
    const int*   g_deg  = (const int*)d_in[6];
    float* g_out = (float*)d_out;

    int N = in_sizes[0] / 3;

    // RES exactly as the reference: python float64 exp/log/pow, cast to fp32.
    ResT rt;
    double scale = exp((log(4096.0) - log(16.0)) / 15.0);
    for (int l = 0; l < NLV; ++l) rt.r[l] = (float)(16.0 * pow(scale, (double)l));

    size_t need = (size_t)NLV * N * 8 * sizeof(float);   // 134 MB at N=262144
    if (ws_size >= need) {
        float* ws = (float*)d_ws;
        int chunks = (N + 255) / 256;
        level_gather<<<NLV * chunks, 256, 0, stream>>>(g_pos, g_tab, g_aabb,
                                                       ws, N, chunks, rt);
        mlp_bwd<<<chunks, 256, 0, stream>>>(g_pos, g_rx, g_W1, g_W2, g_aabb,
                                            g_deg, ws, g_out, N, rt);
    } else {
        long long threads = 2LL * N;
        int blocks = (int)((threads + 255) / 256);
        ngp_fused<<<blocks, 256, 0, stream>>>(g_pos, g_rx, g_tab, g_W1, g_W2,
                                              g_aabb, g_deg, g_out, N, rt);
    }
}